// Round 9
// baseline (2994.014 us; speedup 1.0000x reference)
//
#include <hip/hip_runtime.h>
#include <math.h>

#define S 32
#define T 32
#define B 64
#define H 256
#define MSZ 65536   // elements per swizzled bf16 matrix [8 kt][256 col][32 kk]
#define ROWSP 16
#define FPAD 16     // ints per flag slot (64 B)

typedef __attribute__((ext_vector_type(8))) short s16x8;
typedef __attribute__((ext_vector_type(4))) float f32x4;

__device__ inline unsigned short f2b(float f){
    unsigned u = __builtin_bit_cast(unsigned, f);
    u += 0x7fffu + ((u >> 16) & 1u);          // RNE
    return (unsigned short)(u >> 16);
}
__device__ inline float b2f(unsigned short s){
    unsigned u = ((unsigned)s) << 16;
    return __builtin_bit_cast(float, u);
}
__device__ inline float tanh_fast(float x){
    float e = __builtin_amdgcn_exp2f(x * 2.8853900817779268f);
    float r = __builtin_amdgcn_rcpf(e + 1.0f);
    return fmaf(-2.0f, r, 1.0f);
}
__device__ inline void pollflag(const int* f){
    while (__hip_atomic_load(f, __ATOMIC_RELAXED, __HIP_MEMORY_SCOPE_AGENT) == 0)
        __builtin_amdgcn_s_sleep(1);
    asm volatile("" ::: "memory");
}
// A fragment for mfma_f32_16x16x32_bf16 from row-major f32
__device__ inline s16x8 make_afrag(const float* __restrict__ M, int arow, int k0){
    const float* p = M + arow * H + k0;
    float4 x = *(const float4*)(p);
    float4 y = *(const float4*)(p + 4);
    s16x8 r;
    r[0]=(short)f2b(x.x); r[1]=(short)f2b(x.y); r[2]=(short)f2b(x.z); r[3]=(short)f2b(x.w);
    r[4]=(short)f2b(y.x); r[5]=(short)f2b(y.y); r[6]=(short)f2b(y.z); r[7]=(short)f2b(y.w);
    return r;
}

// ---------------- prep: swizzle U (both depths, top/left) + W[1] to bf16 ----
// Bsw[m][kt][c][kk] = M_m[kt*32+kk][c];  m: 0=U0t 1=U0l 2=U1t 3=U1l 4=W1
__global__ __launch_bounds__(256) void prep_kernel(
    const float* __restrict__ U, const float* __restrict__ W,
    unsigned short* __restrict__ Bsw)
{
    int t = blockIdx.x * 256 + threadIdx.x;
    if (t >= 5 * MSZ) return;
    int m  = t >> 16;
    int r  = t & 65535;
    int kt = r >> 13;
    int r2 = r & 8191;
    int c  = r2 >> 5;
    int kk = r2 & 31;
    int krow = kt * 32 + kk;
    float v;
    if (m < 4){ int d = m >> 1, ope = m & 1; v = U[((size_t)d*2*H + ope*H + krow)*H + c]; }
    else      { v = W[((size_t)H + krow)*H + c]; }   // W[1]
    Bsw[t] = f2b(v);
}

// ---------------- depth-0 projections (bf16 out): sxw = src@W0, tyw = trg@W0
__global__ __launch_bounds__(256) void proj0b_kernel(
    const float* __restrict__ src, const float* __restrict__ trg,
    const float* __restrict__ W0, unsigned short* __restrict__ sxw,
    unsigned short* __restrict__ tyw)
{
    const int c = threadIdx.x;
    int gr0 = blockIdx.x * ROWSP;
    const float* inp; unsigned short* outp; int r0;
    if (gr0 < S * B) { inp = src; outp = sxw; r0 = gr0; }
    else             { inp = trg; outp = tyw; r0 = gr0 - S * B; }

    float acc[ROWSP];
#pragma unroll
    for (int rr = 0; rr < ROWSP; ++rr) acc[rr] = 0.f;
    for (int k = 0; k < H; ++k) {
        float wv = W0[k * H + c];
#pragma unroll
        for (int rr = 0; rr < ROWSP; ++rr)
            acc[rr] = fmaf(inp[(size_t)(r0 + rr) * H + k], wv, acc[rr]);
    }
#pragma unroll
    for (int rr = 0; rr < ROWSP; ++rr)
        outp[(size_t)(r0 + rr) * H + c] = f2b(acc[rr]);
}

__global__ __launch_bounds__(256) void zeroflags_kernel(int* flags, int n){
    int t = blockIdx.x * 256 + threadIdx.x;
    if (t < n) flags[t] = 0;
}

// ---------------- persistent dataflow, full-row blocks, slim bodies --------
// 64 blocks x 512 thr: blk 0..31 = depth0 row i; 32..63 = depth1 row i.
// Left dep internal (LDS image persist [0,32K)); top staged in [32K,64K).
// KEY: the parent(m+1) prefetch poll sits AFTER this cell's flag publish.
__global__ __launch_bounds__(512, 1) void grid_kernel(
    const unsigned short* __restrict__ Bsw,
    const unsigned short* __restrict__ sxwb,
    const unsigned short* __restrict__ tywb,
    const float* __restrict__ bvec,
    float* __restrict__ out,
    int* __restrict__ flags)
{
    __shared__ char lds[65536];

    const int blk  = blockIdx.x;
    const int btyp = blk >> 5;          // 0=d0, 1=d1
    const int i    = blk & 31;

    const int tid  = threadIdx.x;
    const int lane = tid & 63;
    const int wv   = tid >> 6;
    const int colq = lane & 15;
    const int hi   = lane >> 4;
    const int kk0  = hi * 8;
    const int hi16 = hi * 16;
    const int lswz = (colq & 7) << 4;
    const int c0   = wv * 32 + colq;    // col for ct=0; ct=1 -> +16

    const int srow = tid >> 3;          // staging row 0..63
    const int cb   = (tid & 7) * 32;    // staging col base (32 f32)
    const int swzS = (srow & 7) << 4;

    int* f0 = flags;
    int* f1 = flags + S*T*FPAD;

    const size_t CH_ = (size_t)B * H;
#define OPTR(dd,ii,jj,cc) (out + ((((size_t)(dd)*S + (ii))*T + (jj))*2 + (cc)) * CH_)

#define LOADR(Lr, SP) do { \
    const float* _p = (SP) + (size_t)srow * H + cb; \
    _Pragma("unroll") \
    for (int _l = 0; _l < 4; ++_l) { \
        (Lr)[2*_l]   = *(const float4*)(_p + _l*8); \
        (Lr)[2*_l+1] = *(const float4*)(_p + _l*8 + 4); \
    } } while(0)

#define WRITR(BASE, Lr) do { \
    _Pragma("unroll") \
    for (int _l = 0; _l < 4; ++_l) { \
        float4 _a = (Lr)[2*_l], _b = (Lr)[2*_l+1]; \
        uint4 _g; \
        _g.x = f2b(_a.x) | ((unsigned)f2b(_a.y) << 16); \
        _g.y = f2b(_a.z) | ((unsigned)f2b(_a.w) << 16); \
        _g.z = f2b(_b.x) | ((unsigned)f2b(_b.y) << 16); \
        _g.w = f2b(_b.z) | ((unsigned)f2b(_b.w) << 16); \
        *(uint4*)(lds + (BASE) + srow*512 + (((cb*2) + _l*16) ^ swzS)) = _g; \
    } } while(0)

#define AFRAG(BASE, RT, KT) (*(const s16x8*)(lds + (BASE) + ((RT)*16 + colq)*512 + ((((KT)*64) + hi16) ^ lswz)))

#define MMPH_REG(BASE, BF, ACC) do { \
    _Pragma("unroll") \
    for (int _kt = 0; _kt < 8; ++_kt) { \
        s16x8 _a0 = AFRAG(BASE, 0, _kt), _a1 = AFRAG(BASE, 1, _kt); \
        s16x8 _a2 = AFRAG(BASE, 2, _kt), _a3 = AFRAG(BASE, 3, _kt); \
        _Pragma("unroll") \
        for (int _ct = 0; _ct < 2; ++_ct) { \
            ACC[0][_ct] = __builtin_amdgcn_mfma_f32_16x16x32_bf16(_a0, BF[_kt][_ct], ACC[0][_ct], 0, 0, 0); \
            ACC[1][_ct] = __builtin_amdgcn_mfma_f32_16x16x32_bf16(_a1, BF[_kt][_ct], ACC[1][_ct], 0, 0, 0); \
            ACC[2][_ct] = __builtin_amdgcn_mfma_f32_16x16x32_bf16(_a2, BF[_kt][_ct], ACC[2][_ct], 0, 0, 0); \
            ACC[3][_ct] = __builtin_amdgcn_mfma_f32_16x16x32_bf16(_a3, BF[_kt][_ct], ACC[3][_ct], 0, 0, 0); \
        } \
    } } while(0)

#define MMPH_STREAM(BASE, MB, ACC) do { \
    uintptr_t _o = (uintptr_t)(MB); \
    asm volatile("" : "+v"(_o)); \
    const unsigned short* _m = (const unsigned short*)_o; \
    _Pragma("unroll") \
    for (int _kt = 0; _kt < 8; ++_kt) { \
        s16x8 _b0 = *(const s16x8*)(_m + (_kt * H + c0) * 32 + kk0); \
        s16x8 _b1 = *(const s16x8*)(_m + (_kt * H + c0 + 16) * 32 + kk0); \
        s16x8 _a0 = AFRAG(BASE, 0, _kt), _a1 = AFRAG(BASE, 1, _kt); \
        s16x8 _a2 = AFRAG(BASE, 2, _kt), _a3 = AFRAG(BASE, 3, _kt); \
        ACC[0][0] = __builtin_amdgcn_mfma_f32_16x16x32_bf16(_a0, _b0, ACC[0][0], 0, 0, 0); \
        ACC[1][0] = __builtin_amdgcn_mfma_f32_16x16x32_bf16(_a1, _b0, ACC[1][0], 0, 0, 0); \
        ACC[2][0] = __builtin_amdgcn_mfma_f32_16x16x32_bf16(_a2, _b0, ACC[2][0], 0, 0, 0); \
        ACC[3][0] = __builtin_amdgcn_mfma_f32_16x16x32_bf16(_a3, _b0, ACC[3][0], 0, 0, 0); \
        ACC[0][1] = __builtin_amdgcn_mfma_f32_16x16x32_bf16(_a0, _b1, ACC[0][1], 0, 0, 0); \
        ACC[1][1] = __builtin_amdgcn_mfma_f32_16x16x32_bf16(_a1, _b1, ACC[1][1], 0, 0, 0); \
        ACC[2][1] = __builtin_amdgcn_mfma_f32_16x16x32_bf16(_a2, _b1, ACC[2][1], 0, 0, 0); \
        ACC[3][1] = __builtin_amdgcn_mfma_f32_16x16x32_bf16(_a3, _b1, ACC[3][1], 0, 0, 0); \
    } } while(0)

// proj: PX/PY += (hx0|hy0 f32) @ W1 (streamed), A-frags scattered from global
#define PROJ(HXP, HYP, PX, PY) do { \
    uintptr_t _o = (uintptr_t)Bsw; \
    asm volatile("" : "+v"(_o)); \
    const unsigned short* _mW = (const unsigned short*)_o + (size_t)4*MSZ; \
    _Pragma("unroll") \
    for (int _rt = 0; _rt < 4; ++_rt) { PX[_rt][0]=(f32x4)(0.f); PX[_rt][1]=(f32x4)(0.f); \
                                        PY[_rt][0]=(f32x4)(0.f); PY[_rt][1]=(f32x4)(0.f); } \
    _Pragma("unroll") \
    for (int _kt = 0; _kt < 8; ++_kt) { \
        s16x8 _b0 = *(const s16x8*)(_mW + (_kt * H + c0) * 32 + kk0); \
        s16x8 _b1 = *(const s16x8*)(_mW + (_kt * H + c0 + 16) * 32 + kk0); \
        const int _k0 = _kt*32 + kk0; \
        _Pragma("unroll") \
        for (int _rt = 0; _rt < 4; ++_rt) { \
            s16x8 _ax = make_afrag((HXP), _rt*16 + colq, _k0); \
            s16x8 _ay = make_afrag((HYP), _rt*16 + colq, _k0); \
            PX[_rt][0] = __builtin_amdgcn_mfma_f32_16x16x32_bf16(_ax, _b0, PX[_rt][0], 0, 0, 0); \
            PX[_rt][1] = __builtin_amdgcn_mfma_f32_16x16x32_bf16(_ax, _b1, PX[_rt][1], 0, 0, 0); \
            PY[_rt][0] = __builtin_amdgcn_mfma_f32_16x16x32_bf16(_ay, _b0, PY[_rt][0], 0, 0, 0); \
            PY[_rt][1] = __builtin_amdgcn_mfma_f32_16x16x32_bf16(_ay, _b1, PY[_rt][1], 0, 0, 0); \
        } \
    } } while(0)

    if (btyp == 0) {
        // ===================== depth-0 row block =====================
        s16x8 bfL[8][2];
#pragma unroll
        for (int kt = 0; kt < 8; ++kt)
#pragma unroll
            for (int ct = 0; ct < 2; ++ct)
                bfL[kt][ct] = *(const s16x8*)(Bsw + (size_t)MSZ + (kt*H + c0 + ct*16)*32 + kk0);
        const float bb0 = bvec[c0], bb1 = bvec[c0 + 16];
        unsigned short xwr[32], ywr[32];
        {
            const unsigned short* xwp = sxwb + (size_t)i * CH_;
            const unsigned short* ywp = tywb;   // row j=0
#pragma unroll
            for (int rt = 0; rt < 4; ++rt)
#pragma unroll
                for (int ct = 0; ct < 2; ++ct)
#pragma unroll
                    for (int q = 0; q < 4; ++q) {
                        int idx = (rt*4+q)*2+ct;
                        size_t off = (size_t)(rt*16 + hi*4 + q) * H + c0 + ct*16;
                        xwr[idx] = xwp[off];
                        ywr[idx] = ywp[off];
                    }
        }
        if (i > 0) {   // startup stage of top col 0
            if (lane == 0) pollflag(&f0[((i-1)*T + 0)*FPAD]);
            float4 Lr[8];
            LOADR(Lr, OPTR(0, i-1, 0, 0));
            WRITR(32768, Lr);
        }

        for (int m = 0; m < T; ++m) {
            __syncthreads();   // B0: staged top + left image ready
            f32x4 acc[4][2];
#pragma unroll
            for (int rt = 0; rt < 4; ++rt) { acc[rt][0] = (f32x4)(0.f); acc[rt][1] = (f32x4)(0.f); }
            if (m > 0) MMPH_REG(0, bfL, acc);
            if (i > 0) MMPH_STREAM(32768, Bsw, acc);
            __syncthreads();   // B1: LDS reads done

            float recs[32];
            float* ox = OPTR(0, i, m, 0);
            float* oy = OPTR(0, i, m, 1);
#pragma unroll
            for (int rt = 0; rt < 4; ++rt)
#pragma unroll
                for (int ct = 0; ct < 2; ++ct) {
                    const float bb = ct ? bb1 : bb0;
                    const int col = c0 + ct*16;
#pragma unroll
                    for (int q = 0; q < 4; ++q) {
                        int idx = (rt*4+q)*2+ct;
                        int r = rt*16 + hi*4 + q;
                        float rec = acc[rt][ct][q] + bb;
                        recs[idx] = rec;
                        float hx = tanh_fast(b2f(xwr[idx]) + rec);
                        __hip_atomic_store(&ox[r*H + col], hx, __ATOMIC_RELAXED, __HIP_MEMORY_SCOPE_AGENT);
                        *(unsigned short*)(lds + r*512 + ((col*2) ^ ((r&7)<<4))) = f2b(hx);
                    }
                }
#pragma unroll
            for (int rt = 0; rt < 4; ++rt)
#pragma unroll
                for (int ct = 0; ct < 2; ++ct) {
                    const int col = c0 + ct*16;
#pragma unroll
                    for (int q = 0; q < 4; ++q) {
                        int idx = (rt*4+q)*2+ct;
                        int r = rt*16 + hi*4 + q;
                        float hy = tanh_fast(b2f(ywr[idx]) + recs[idx]);
                        __hip_atomic_store(&oy[r*H + col], hy, __ATOMIC_RELAXED, __HIP_MEMORY_SCOPE_AGENT);
                    }
                }
            asm volatile("s_waitcnt vmcnt(0)" ::: "memory");
            __syncthreads();   // B2: all stores drained
            if (tid == 0)
                __hip_atomic_store(&f0[(i*T + m)*FPAD], 1, __ATOMIC_RELAXED, __HIP_MEMORY_SCOPE_AGENT);

            // ---- tail (AFTER publish): prefetch yw(m+1) + top(m+1) ----
            if (m + 1 < T) {
                const unsigned short* ywp = tywb + (size_t)(m+1) * CH_;
#pragma unroll
                for (int rt = 0; rt < 4; ++rt)
#pragma unroll
                    for (int ct = 0; ct < 2; ++ct)
#pragma unroll
                        for (int q = 0; q < 4; ++q)
                            ywr[(rt*4+q)*2+ct] = ywp[(size_t)(rt*16 + hi*4 + q) * H + c0 + ct*16];
                if (i > 0) {
                    if (lane == 0) pollflag(&f0[((i-1)*T + m+1)*FPAD]);
                    float4 Lr[8];
                    LOADR(Lr, OPTR(0, i-1, m+1, 0));
                    WRITR(32768, Lr);
                }
            }
        }
    } else {
        // ===================== depth-1 row block =====================
        s16x8 bfL1[8][2];
#pragma unroll
        for (int kt = 0; kt < 8; ++kt)
#pragma unroll
            for (int ct = 0; ct < 2; ++ct)
                bfL1[kt][ct] = *(const s16x8*)(Bsw + (size_t)3*MSZ + (kt*H + c0 + ct*16)*32 + kk0);
        const float bb0 = bvec[H + c0], bb1 = bvec[H + c0 + 16];

        f32x4 px[4][2], py[4][2];
        {   // startup: proj for m=0
            if (lane == 0) pollflag(&f0[(i*T + 0)*FPAD]);
            PROJ(OPTR(0, i, 0, 0), OPTR(0, i, 0, 1), px, py);
        }
        if (i > 0) {   // startup stage of top col 0
            if (lane == 0) pollflag(&f1[((i-1)*T + 0)*FPAD]);
            float4 Lr[8];
            LOADR(Lr, OPTR(1, i-1, 0, 0));
            WRITR(32768, Lr);
        }

        for (int m = 0; m < T; ++m) {
            __syncthreads();   // B0
            f32x4 acc[4][2];
#pragma unroll
            for (int rt = 0; rt < 4; ++rt) { acc[rt][0] = (f32x4)(0.f); acc[rt][1] = (f32x4)(0.f); }
            if (m > 0) MMPH_REG(0, bfL1, acc);
            if (i > 0) MMPH_STREAM(32768, Bsw + (size_t)2*MSZ, acc);
            __syncthreads();   // B1

            float recs[32];
            float* ox = OPTR(1, i, m, 0);
#pragma unroll
            for (int rt = 0; rt < 4; ++rt)
#pragma unroll
                for (int ct = 0; ct < 2; ++ct) {
                    const float bb = ct ? bb1 : bb0;
                    const int col = c0 + ct*16;
#pragma unroll
                    for (int q = 0; q < 4; ++q) {
                        int idx = (rt*4+q)*2+ct;
                        int r = rt*16 + hi*4 + q;
                        float rec = acc[rt][ct][q] + bb;
                        recs[idx] = rec;
                        float hx = tanh_fast(px[rt][ct][q] + rec);
                        __hip_atomic_store(&ox[r*H + col], hx, __ATOMIC_RELAXED, __HIP_MEMORY_SCOPE_AGENT);
                        *(unsigned short*)(lds + r*512 + ((col*2) ^ ((r&7)<<4))) = f2b(hx);
                    }
                }
            asm volatile("s_waitcnt vmcnt(0)" ::: "memory");
            __syncthreads();   // B2
            if (tid == 0)
                __hip_atomic_store(&f1[(i*T + m)*FPAD], 1, __ATOMIC_RELAXED, __HIP_MEMORY_SCOPE_AGENT);

            // hy1 (dead-end) after publish
            {
                float* oy = OPTR(1, i, m, 1);
#pragma unroll
                for (int rt = 0; rt < 4; ++rt)
#pragma unroll
                    for (int ct = 0; ct < 2; ++ct) {
                        const int col = c0 + ct*16;
#pragma unroll
                        for (int q = 0; q < 4; ++q) {
                            int idx = (rt*4+q)*2+ct;
                            int r = rt*16 + hi*4 + q;
                            float hy = tanh_fast(py[rt][ct][q] + recs[idx]);
                            __hip_atomic_store(&oy[r*H + col], hy, __ATOMIC_RELAXED, __HIP_MEMORY_SCOPE_AGENT);
                        }
                    }
            }

            // ---- tail (AFTER publish): top(m+1) stage + proj(m+1) ----
            if (m + 1 < T) {
                float4 LrT[8];
                bool havetop = (i > 0);
                if (havetop) {
                    if (lane == 0) pollflag(&f1[((i-1)*T + m+1)*FPAD]);
                    LOADR(LrT, OPTR(1, i-1, m+1, 0));   // issue loads early
                }
                if (lane == 0) pollflag(&f0[(i*T + m+1)*FPAD]);
                PROJ(OPTR(0, i, m+1, 0), OPTR(0, i, m+1, 1), px, py);   // overlaps top loads
                if (havetop) WRITR(32768, LrT);
            }
        }
    }
#undef OPTR
#undef LOADR
#undef WRITR
#undef AFRAG
#undef MMPH_REG
#undef MMPH_STREAM
#undef PROJ
}

// =================== staged fallback (round-2 structure) ===================
__global__ __launch_bounds__(64) void stage_kernel(
    const unsigned short* __restrict__ Bsw,
    const unsigned short* __restrict__ sxwb,
    const unsigned short* __restrict__ tywb,
    const float* __restrict__ bvec,
    float* __restrict__ out, int v)
{
    const int lane = threadIdx.x;
    const int cellid = blockIdx.x >> 2;
    const int stripe = blockIdx.x & 3;

    int ilo0 = (v > T-1) ? v-(T-1) : 0, ihi0 = (v < S-1) ? v : S-1;
    int n0 = (v <= S+T-2) ? (ihi0 - ilo0 + 1) : 0;
    if (n0 < 0) n0 = 0;
    int w1 = v - 1;
    int ilo1 = (w1 > T-1) ? w1-(T-1) : 0;

    int d, i, j;
    if (cellid < n0) { d = 0; i = ilo0 + cellid; j = v - i; }
    else             { d = 1; int q = cellid - n0; i = ilo1 + q; j = w1 - i; }

    const int r0   = stripe * 16;
    const int arow = r0 + (lane & 15);
    const int kk0  = (lane >> 4) * 8;
    const int colq = lane & 15;
    const int rowq = r0 + ((lane >> 4) << 2);

#define OUTB(dd,ii,jj,cc) (out + ((((size_t)(dd)*S + (ii))*T + (jj))*2 + (cc)) * (size_t)(B*H))

    if (d == 0) {
        f32x4 acc[16];
#pragma unroll
        for (int t = 0; t < 16; ++t) acc[t] = (f32x4)(0.f);
        if (i > 0) {
            const float* topM = OUTB(0, i-1, j, 0);
            const unsigned short* Bt = Bsw + 0*MSZ;
            for (int kt = 0; kt < 8; ++kt) {
                s16x8 a = make_afrag(topM, arow, kt*32 + kk0);
                const unsigned short* bp = Bt + (kt*H + colq)*32 + kk0;
#pragma unroll
                for (int ct = 0; ct < 16; ++ct)
                    acc[ct] = __builtin_amdgcn_mfma_f32_16x16x32_bf16(a, *(const s16x8*)(bp + ct*512), acc[ct], 0, 0, 0);
            }
        }
        if (j > 0) {
            const float* lftM = OUTB(0, i, j-1, 0);
            const unsigned short* Bl = Bsw + 1*MSZ;
            for (int kt = 0; kt < 8; ++kt) {
                s16x8 a = make_afrag(lftM, arow, kt*32 + kk0);
                const unsigned short* bp = Bl + (kt*H + colq)*32 + kk0;
#pragma unroll
                for (int ct = 0; ct < 16; ++ct)
                    acc[ct] = __builtin_amdgcn_mfma_f32_16x16x32_bf16(a, *(const s16x8*)(bp + ct*512), acc[ct], 0, 0, 0);
            }
        }
        const unsigned short* xwp = sxwb + (size_t)i * B * H;
        const unsigned short* ywp = tywb + (size_t)j * B * H;
        float* ox = OUTB(0, i, j, 0);
        float* oy = OUTB(0, i, j, 1);
#pragma unroll
        for (int ct = 0; ct < 16; ++ct) {
            int col = ct*16 + colq;
            float bc = bvec[col];
#pragma unroll
            for (int q = 0; q < 4; ++q) {
                int row = rowq + q;
                float rec = acc[ct][q] + bc;
                ox[row*H + col] = tanh_fast(b2f(xwp[row*H + col]) + rec);
                oy[row*H + col] = tanh_fast(b2f(ywp[row*H + col]) + rec);
            }
        }
    } else {
        const float* hx0 = OUTB(0, i, j, 0);
        const float* hy0 = OUTB(0, i, j, 1);
        const float* topM = (i > 0) ? OUTB(1, i-1, j, 0) : (const float*)0;
        const float* lftM = (j > 0) ? OUTB(1, i, j-1, 0) : (const float*)0;
        const unsigned short* BU1t = Bsw + 2*MSZ;
        const unsigned short* BU1l = Bsw + 3*MSZ;
        const unsigned short* BW1  = Bsw + 4*MSZ;
        float* ox = OUTB(1, i, j, 0);
        float* oy = OUTB(1, i, j, 1);

        for (int halfc = 0; halfc < 2; ++halfc) {
            f32x4 arr[8], axx[8], ayy[8];
#pragma unroll
            for (int t = 0; t < 8; ++t) { arr[t]=(f32x4)(0.f); axx[t]=(f32x4)(0.f); ayy[t]=(f32x4)(0.f); }
            const int bbase = halfc*4096 + colq*32 + kk0;

            for (int kt = 0; kt < 8; ++kt) {
                const int k0 = kt*32 + kk0;
                const int bofs = kt*H*32 + bbase;
                if (topM) {
                    s16x8 a = make_afrag(topM, arow, k0);
#pragma unroll
                    for (int ct = 0; ct < 8; ++ct)
                        arr[ct] = __builtin_amdgcn_mfma_f32_16x16x32_bf16(a, *(const s16x8*)(BU1t + bofs + ct*512), arr[ct], 0, 0, 0);
                }
                if (lftM) {
                    s16x8 a = make_afrag(lftM, arow, k0);
#pragma unroll
                    for (int ct = 0; ct < 8; ++ct)
                        arr[ct] = __builtin_amdgcn_mfma_f32_16x16x32_bf16(a, *(const s16x8*)(BU1l + bofs + ct*512), arr[ct], 0, 0, 0);
                }
                {
                    s16x8 a = make_afrag(hx0, arow, k0);
#pragma unroll
                    for (int ct = 0; ct < 8; ++ct)
                        axx[ct] = __builtin_amdgcn_mfma_f32_16x16x32_bf16(a, *(const s16x8*)(BW1 + bofs + ct*512), axx[ct], 0, 0, 0);
                }
                {
                    s16x8 a = make_afrag(hy0, arow, k0);
#pragma unroll
                    for (int ct = 0; ct < 8; ++ct)
                        ayy[ct] = __builtin_amdgcn_mfma_f32_16x16x32_bf16(a, *(const s16x8*)(BW1 + bofs + ct*512), ayy[ct], 0, 0, 0);
                }
            }
#pragma unroll
            for (int ct = 0; ct < 8; ++ct) {
                int col = halfc*128 + ct*16 + colq;
                float bc = bvec[H + col];
#pragma unroll
                for (int q = 0; q < 4; ++q) {
                    int row = rowq + q;
                    float rec = arr[ct][q] + bc;
                    ox[row*H + col] = tanh_fast(axx[ct][q] + rec);
                    oy[row*H + col] = tanh_fast(ayy[ct][q] + rec);
                }
            }
        }
    }
#undef OUTB
}

// ============================ host launcher ================================
extern "C" void kernel_launch(void* const* d_in, const int* in_sizes, int n_in,
                              void* d_out, int out_size, void* d_ws, size_t ws_size,
                              hipStream_t stream)
{
    const float* src = (const float*)d_in[0];
    const float* trg = (const float*)d_in[1];
    const float* W   = (const float*)d_in[2];
    const float* U   = (const float*)d_in[3];
    const float* b   = (const float*)d_in[4];
    float* out = (float*)d_out;

    const int nflags = 2 * S * T * FPAD;
    const size_t need_stage   = (size_t)5*MSZ*2 + (size_t)2*S*B*H*2;
    const size_t need_persist = need_stage + (size_t)nflags*sizeof(int);

    unsigned short* Bsw  = (unsigned short*)d_ws;
    unsigned short* sxwb = Bsw + (size_t)5*MSZ;
    unsigned short* tywb = sxwb + (size_t)S*B*H;
    int* flags = (int*)(tywb + (size_t)S*B*H);

    prep_kernel<<<(5*MSZ + 255)/256, 256, 0, stream>>>(U, W, Bsw);
    proj0b_kernel<<<2*S*B/ROWSP, 256, 0, stream>>>(src, trg, W, sxwb, tywb);

    if (ws_size >= need_persist) {
        zeroflags_kernel<<<(nflags + 255)/256, 256, 0, stream>>>(flags, nflags);
        grid_kernel<<<64, 512, 0, stream>>>(Bsw, sxwb, tywb, b, out, flags);
        return;
    }

    // -------- staged fallback --------
    for (int v = 0; v < S + T; ++v) {
        int ilo0 = (v > T-1) ? v-(T-1) : 0, ihi0 = (v < S-1) ? v : S-1;
        int n0 = (v <= S+T-2) ? (ihi0 - ilo0 + 1) : 0;
        if (n0 < 0) n0 = 0;
        int n1 = 0;
        int w1 = v - 1;
        if (w1 >= 0) {
            int ilo1 = (w1 > T-1) ? w1-(T-1) : 0, ihi1 = (w1 < S-1) ? w1 : S-1;
            n1 = ihi1 - ilo1 + 1;
        }
        stage_kernel<<<4*(n0+n1), 64, 0, stream>>>(Bsw, sxwb, tywb, b, out, v);
    }
}

// Round 10
// 847.469 us; speedup vs baseline: 3.5329x; 3.5329x over previous
//
#include <hip/hip_runtime.h>
#include <math.h>

#define S 32
#define T 32
#define B 64
#define H 256
#define MSZ 65536   // elements per swizzled bf16 matrix [8 kt][256 col][32 kk]
#define ROWSP 16

typedef __attribute__((ext_vector_type(8))) short s16x8;
typedef __attribute__((ext_vector_type(4))) float f32x4;

__device__ inline unsigned short f2b(float f){
    unsigned u = __builtin_bit_cast(unsigned, f);
    u += 0x7fffu + ((u >> 16) & 1u);          // RNE
    return (unsigned short)(u >> 16);
}
__device__ inline float b2f(unsigned short s){
    unsigned u = ((unsigned)s) << 16;
    return __builtin_bit_cast(float, u);
}
__device__ inline float tanh_fast(float x){
    float e = __builtin_amdgcn_exp2f(x * 2.8853900817779268f);
    float r = __builtin_amdgcn_rcpf(e + 1.0f);
    return fmaf(-2.0f, r, 1.0f);
}
__device__ inline void waitflag(int* f, int target){
    while (__hip_atomic_load(f, __ATOMIC_RELAXED, __HIP_MEMORY_SCOPE_AGENT) < target)
        __builtin_amdgcn_s_sleep(2);
    (void)__hip_atomic_load(f, __ATOMIC_ACQUIRE, __HIP_MEMORY_SCOPE_AGENT);
}

// ---------------- prep: swizzle U (both depths, top/left) + W[1] to bf16 ----
// Bsw[m][kt][c][kk] = M_m[kt*32+kk][c];  m: 0=U0t 1=U0l 2=U1t 3=U1l 4=W1
__global__ __launch_bounds__(256) void prep_kernel(
    const float* __restrict__ U, const float* __restrict__ W,
    unsigned short* __restrict__ Bsw)
{
    int t = blockIdx.x * 256 + threadIdx.x;
    if (t >= 5 * MSZ) return;
    int m  = t >> 16;
    int r  = t & 65535;
    int kt = r >> 13;
    int r2 = r & 8191;
    int c  = r2 >> 5;
    int kk = r2 & 31;
    int krow = kt * 32 + kk;
    float v;
    if (m < 4){ int d = m >> 1, ope = m & 1; v = U[((size_t)d*2*H + ope*H + krow)*H + c]; }
    else      { v = W[((size_t)H + krow)*H + c]; }   // W[1]
    Bsw[t] = f2b(v);
}

// ---------------- depth-0 projections (bf16 out): sxw = src@W0, tyw = trg@W0
__global__ __launch_bounds__(256) void proj0b_kernel(
    const float* __restrict__ src, const float* __restrict__ trg,
    const float* __restrict__ W0, unsigned short* __restrict__ sxw,
    unsigned short* __restrict__ tyw)
{
    const int c = threadIdx.x;
    int gr0 = blockIdx.x * ROWSP;
    const float* inp; unsigned short* outp; int r0;
    if (gr0 < S * B) { inp = src; outp = sxw; r0 = gr0; }
    else             { inp = trg; outp = tyw; r0 = gr0 - S * B; }

    float acc[ROWSP];
#pragma unroll
    for (int rr = 0; rr < ROWSP; ++rr) acc[rr] = 0.f;
    for (int k = 0; k < H; ++k) {
        float wv = W0[k * H + c];
#pragma unroll
        for (int rr = 0; rr < ROWSP; ++rr)
            acc[rr] = fmaf(inp[(size_t)(r0 + rr) * H + k], wv, acc[rr]);
    }
#pragma unroll
    for (int rr = 0; rr < ROWSP; ++rr)
        outp[(size_t)(r0 + rr) * H + c] = f2b(acc[rr]);
}

__global__ __launch_bounds__(256) void zeroflags_kernel(int* flags, int n){
    int t = blockIdx.x * 256 + threadIdx.x;
    if (t < n) flags[t] = 0;
}

// ---------------- persistent dataflow grid kernel (champion structure) -----
// 128 blocks: blk 0..63 = depth0 (row=blk>>1 of low 6 bits, half=blk&1),
// 64..127 = depth1. Block walks j=0..31; flags flag0/flag1 count completed
// col-halves (target 2). Acquire polls, single release fetch_add per hop,
// chunked staging with next-chunk loads prefetched under current MFMAs.
__global__ __launch_bounds__(512, 2) void grid_kernel(
    const unsigned short* __restrict__ Bsw,
    const unsigned short* __restrict__ sxwb,
    const unsigned short* __restrict__ tywb,
    const float* __restrict__ bvec,
    float* __restrict__ out,
    int* __restrict__ flags)
{
    __shared__ unsigned short Alds[4 * 64 * 128];   // 64 KB
    char* AldsB = (char*)Alds;

    const int blk   = blockIdx.x;
    const int depth = blk >> 6;
    const int i     = (blk & 63) >> 1;
    const int half  = blk & 1;
    const int c0    = half * 128;

    const int tid  = threadIdx.x;
    const int lane = tid & 63;
    const int wv   = tid >> 6;          // wave 0..7, owns 16 cols
    const int colq = lane & 15;
    const int hi   = lane >> 4;
    const int kk0  = hi * 8;
    const int col  = c0 + wv * 16 + colq;
    const int hi16 = hi * 16;
    const int lswz = (colq & 7) << 4;   // A-frag read swizzle (row&7 == colq&7)

    const int row64 = tid >> 3;         // staging row 0..63
    const int k4b   = (tid & 7) * 4;    // staging float4 base within 32
    const int swz   = (row64 & 7) << 4; // staging write swizzle

    int* flag0 = flags;
    int* flag1 = flags + S * T;

    // persistent B fragments in VGPRs
    s16x8 bfT[8], bfL[8], bfW[8];
    {
        const unsigned short* mT = Bsw + (size_t)(depth == 0 ? 0 : 2) * MSZ;
        const unsigned short* mL = Bsw + (size_t)(depth == 0 ? 1 : 3) * MSZ;
        const unsigned short* mW = Bsw + (size_t)4 * MSZ;
#pragma unroll
        for (int kt = 0; kt < 8; ++kt) {
            int o = (kt * H + col) * 32 + kk0;
            bfT[kt] = *(const s16x8*)(mT + o);
            bfL[kt] = *(const s16x8*)(mL + o);
            bfW[kt] = *(const s16x8*)(mW + o);
        }
    }

    const size_t CH = (size_t)B * H;
#define OPTR(dd,ii,jj,ch) (out + ((((size_t)(dd)*S + (ii))*T + (jj))*2 + (ch)) * CH)

#define LOADOP(OP, SP, KC) do { \
    const float* _s = (SP); \
    if (_s) { const float* _p = _s + (size_t)row64 * H + (KC)*128 + k4b*4; \
        L[(OP)*4+0] = *(const float4*)(_p); \
        L[(OP)*4+1] = *(const float4*)(_p + 4); \
        L[(OP)*4+2] = *(const float4*)(_p + 8); \
        L[(OP)*4+3] = *(const float4*)(_p + 12); } \
    else { float4 _z = {0.f,0.f,0.f,0.f}; \
        L[(OP)*4+0]=_z; L[(OP)*4+1]=_z; L[(OP)*4+2]=_z; L[(OP)*4+3]=_z; } \
} while(0)

#define WRITEOP(OP) do { \
    _Pragma("unroll") \
    for (int _l = 0; _l < 4; ++_l) { \
        float4 _v = L[(OP)*4+_l]; \
        uint2 _u; \
        _u.x = f2b(_v.x) | ((unsigned)f2b(_v.y) << 16); \
        _u.y = f2b(_v.z) | ((unsigned)f2b(_v.w) << 16); \
        *(uint2*)(AldsB + (OP)*16384 + row64*256 + (((k4b+_l)*8) ^ swz)) = _u; \
    } \
} while(0)

#define AFRAG(OP, RT, KTL) (*(const s16x8*)(AldsB + (OP)*16384 + ((RT)*16 + colq)*256 + ((((KTL)*64) + hi16) ^ lswz)))

    if (depth == 0) {
        // xw is j-invariant: hoist into registers once (edit 1)
        unsigned short xwr[16];
        {
            const unsigned short* xwp = sxwb + (size_t)i * B * H;
#pragma unroll
            for (int rt = 0; rt < 4; ++rt)
#pragma unroll
                for (int q = 0; q < 4; ++q)
                    xwr[rt*4+q] = xwp[(size_t)(rt*16 + hi*4 + q) * H + col];
        }

        for (int j = 0; j < T; ++j) {
            // yw: issue loads at loop top so latency hides under staging/MFMAs (edit 2)
            unsigned short ywr[16];
            {
                const unsigned short* ywp = tywb + (size_t)j * B * H;
#pragma unroll
                for (int rt = 0; rt < 4; ++rt)
#pragma unroll
                    for (int q = 0; q < 4; ++q)
                        ywr[rt*4+q] = ywp[(size_t)(rt*16 + hi*4 + q) * H + col];
            }
            if (tid == 0) {
                if (i > 0) waitflag(&flag0[(i-1)*T + j], 2);
                if (j > 0) waitflag(&flag0[i*T + (j-1)], 2);
            }
            __syncthreads();

            const float* sTop  = (i > 0) ? OPTR(0, i-1, j, 0) : (const float*)0;
            const float* sLeft = (j > 0) ? OPTR(0, i, j-1, 0) : (const float*)0;

            f32x4 acc[4];
#pragma unroll
            for (int rt = 0; rt < 4; ++rt) acc[rt] = (f32x4)(0.f);

            float4 L[16];

            LOADOP(0, sTop, 0); LOADOP(1, sLeft, 0);
            WRITEOP(0); WRITEOP(1);
            __syncthreads();
            LOADOP(0, sTop, 1); LOADOP(1, sLeft, 1);     // prefetch chunk 1
#pragma unroll
            for (int ktl = 0; ktl < 4; ++ktl)
#pragma unroll
                for (int rt = 0; rt < 4; ++rt) {
                    acc[rt] = __builtin_amdgcn_mfma_f32_16x16x32_bf16(AFRAG(0,rt,ktl), bfT[ktl], acc[rt], 0, 0, 0);
                    acc[rt] = __builtin_amdgcn_mfma_f32_16x16x32_bf16(AFRAG(1,rt,ktl), bfL[ktl], acc[rt], 0, 0, 0);
                }
            __syncthreads();
            WRITEOP(0); WRITEOP(1);
            __syncthreads();
#pragma unroll
            for (int ktl = 0; ktl < 4; ++ktl)
#pragma unroll
                for (int rt = 0; rt < 4; ++rt) {
                    acc[rt] = __builtin_amdgcn_mfma_f32_16x16x32_bf16(AFRAG(0,rt,ktl), bfT[4+ktl], acc[rt], 0, 0, 0);
                    acc[rt] = __builtin_amdgcn_mfma_f32_16x16x32_bf16(AFRAG(1,rt,ktl), bfL[4+ktl], acc[rt], 0, 0, 0);
                }
            __syncthreads();

            float* ox = OPTR(0, i, j, 0);
            float* oy = OPTR(0, i, j, 1);
            const float bc = bvec[col];
#pragma unroll
            for (int rt = 0; rt < 4; ++rt)
#pragma unroll
                for (int q = 0; q < 4; ++q) {
                    int idx = rt*4 + q;
                    int row = rt*16 + hi*4 + q;
                    float rec = acc[rt][q] + bc;
                    float hx = tanh_fast(b2f(xwr[idx]) + rec);
                    float hy = tanh_fast(b2f(ywr[idx]) + rec);
                    __hip_atomic_store(&ox[row*H + col], hx, __ATOMIC_RELAXED, __HIP_MEMORY_SCOPE_AGENT);
                    __hip_atomic_store(&oy[row*H + col], hy, __ATOMIC_RELAXED, __HIP_MEMORY_SCOPE_AGENT);
                }

            // publish
            asm volatile("s_waitcnt vmcnt(0)" ::: "memory");
            __syncthreads();
            if (tid == 0)
                __hip_atomic_fetch_add(&flag0[i*T + j], 1, __ATOMIC_RELEASE, __HIP_MEMORY_SCOPE_AGENT);
        }
    } else {
        for (int j = 0; j < T; ++j) {
            if (tid == 0) {
                waitflag(&flag0[i*T + j], 2);
                if (i > 0) waitflag(&flag1[(i-1)*T + j], 2);
                if (j > 0) waitflag(&flag1[i*T + (j-1)], 2);
            }
            __syncthreads();

            const float* sTop  = (i > 0) ? OPTR(1, i-1, j, 0) : (const float*)0;
            const float* sLeft = (j > 0) ? OPTR(1, i, j-1, 0) : (const float*)0;
            const float* sHx0  = OPTR(0, i, j, 0);
            const float* sHy0  = OPTR(0, i, j, 1);

            f32x4 ar[4], ax[4], ay[4];
#pragma unroll
            for (int rt = 0; rt < 4; ++rt){ ar[rt] = (f32x4)(0.f); ax[rt] = (f32x4)(0.f); ay[rt] = (f32x4)(0.f); }

            float4 L[16];

            LOADOP(0, sTop, 0); LOADOP(1, sLeft, 0); LOADOP(2, sHx0, 0); LOADOP(3, sHy0, 0);
            WRITEOP(0); WRITEOP(1); WRITEOP(2); WRITEOP(3);
            __syncthreads();
            LOADOP(0, sTop, 1); LOADOP(1, sLeft, 1); LOADOP(2, sHx0, 1); LOADOP(3, sHy0, 1);
#pragma unroll
            for (int ktl = 0; ktl < 4; ++ktl)
#pragma unroll
                for (int rt = 0; rt < 4; ++rt) {
                    ar[rt] = __builtin_amdgcn_mfma_f32_16x16x32_bf16(AFRAG(0,rt,ktl), bfT[ktl], ar[rt], 0, 0, 0);
                    ar[rt] = __builtin_amdgcn_mfma_f32_16x16x32_bf16(AFRAG(1,rt,ktl), bfL[ktl], ar[rt], 0, 0, 0);
                    ax[rt] = __builtin_amdgcn_mfma_f32_16x16x32_bf16(AFRAG(2,rt,ktl), bfW[ktl], ax[rt], 0, 0, 0);
                    ay[rt] = __builtin_amdgcn_mfma_f32_16x16x32_bf16(AFRAG(3,rt,ktl), bfW[ktl], ay[rt], 0, 0, 0);
                }
            __syncthreads();
            WRITEOP(0); WRITEOP(1); WRITEOP(2); WRITEOP(3);
            __syncthreads();
#pragma unroll
            for (int ktl = 0; ktl < 4; ++ktl)
#pragma unroll
                for (int rt = 0; rt < 4; ++rt) {
                    ar[rt] = __builtin_amdgcn_mfma_f32_16x16x32_bf16(AFRAG(0,rt,ktl), bfT[4+ktl], ar[rt], 0, 0, 0);
                    ar[rt] = __builtin_amdgcn_mfma_f32_16x16x32_bf16(AFRAG(1,rt,ktl), bfL[4+ktl], ar[rt], 0, 0, 0);
                    ax[rt] = __builtin_amdgcn_mfma_f32_16x16x32_bf16(AFRAG(2,rt,ktl), bfW[4+ktl], ax[rt], 0, 0, 0);
                    ay[rt] = __builtin_amdgcn_mfma_f32_16x16x32_bf16(AFRAG(3,rt,ktl), bfW[4+ktl], ay[rt], 0, 0, 0);
                }
            __syncthreads();

            float* ox = OPTR(1, i, j, 0);
            float* oy = OPTR(1, i, j, 1);
            const float bc = bvec[H + col];
#pragma unroll
            for (int rt = 0; rt < 4; ++rt)
#pragma unroll
                for (int q = 0; q < 4; ++q) {
                    int row = rt*16 + hi*4 + q;
                    float rec = ar[rt][q] + bc;
                    float hx = tanh_fast(ax[rt][q] + rec);
                    float hy = tanh_fast(ay[rt][q] + rec);
                    __hip_atomic_store(&ox[row*H + col], hx, __ATOMIC_RELAXED, __HIP_MEMORY_SCOPE_AGENT);
                    __hip_atomic_store(&oy[row*H + col], hy, __ATOMIC_RELAXED, __HIP_MEMORY_SCOPE_AGENT);
                }

            // publish
            asm volatile("s_waitcnt vmcnt(0)" ::: "memory");
            __syncthreads();
            if (tid == 0)
                __hip_atomic_fetch_add(&flag1[i*T + j], 1, __ATOMIC_RELEASE, __HIP_MEMORY_SCOPE_AGENT);
        }
    }
#undef OPTR
#undef LOADOP
#undef WRITEOP
#undef AFRAG
}

// =================== staged fallback (round-2 structure) ===================
__device__ inline s16x8 make_afrag(const float* __restrict__ M, int arow, int k0){
    const float* p = M + arow * H + k0;
    float4 x = *(const float4*)(p);
    float4 y = *(const float4*)(p + 4);
    s16x8 r;
    r[0]=(short)f2b(x.x); r[1]=(short)f2b(x.y); r[2]=(short)f2b(x.z); r[3]=(short)f2b(x.w);
    r[4]=(short)f2b(y.x); r[5]=(short)f2b(y.y); r[6]=(short)f2b(y.z); r[7]=(short)f2b(y.w);
    return r;
}

__global__ __launch_bounds__(64) void stage_kernel(
    const unsigned short* __restrict__ Bsw,
    const unsigned short* __restrict__ sxwb,
    const unsigned short* __restrict__ tywb,
    const float* __restrict__ bvec,
    float* __restrict__ out, int v)
{
    const int lane = threadIdx.x;
    const int cellid = blockIdx.x >> 2;
    const int stripe = blockIdx.x & 3;

    int ilo0 = (v > T-1) ? v-(T-1) : 0, ihi0 = (v < S-1) ? v : S-1;
    int n0 = (v <= S+T-2) ? (ihi0 - ilo0 + 1) : 0;
    if (n0 < 0) n0 = 0;
    int w1 = v - 1;
    int ilo1 = (w1 > T-1) ? w1-(T-1) : 0;

    int d, i, j;
    if (cellid < n0) { d = 0; i = ilo0 + cellid; j = v - i; }
    else             { d = 1; int q = cellid - n0; i = ilo1 + q; j = w1 - i; }

    const int r0   = stripe * 16;
    const int arow = r0 + (lane & 15);
    const int kk0  = (lane >> 4) * 8;
    const int colq = lane & 15;
    const int rowq = r0 + ((lane >> 4) << 2);

#define OUTB(dd,ii,jj,ch) (out + ((((size_t)(dd)*S + (ii))*T + (jj))*2 + (ch)) * (size_t)(B*H))

    if (d == 0) {
        f32x4 acc[16];
#pragma unroll
        for (int t = 0; t < 16; ++t) acc[t] = (f32x4)(0.f);
        if (i > 0) {
            const float* topM = OUTB(0, i-1, j, 0);
            const unsigned short* Bt = Bsw + 0*MSZ;
            for (int kt = 0; kt < 8; ++kt) {
                s16x8 a = make_afrag(topM, arow, kt*32 + kk0);
                const unsigned short* bp = Bt + (kt*H + colq)*32 + kk0;
#pragma unroll
                for (int ct = 0; ct < 16; ++ct)
                    acc[ct] = __builtin_amdgcn_mfma_f32_16x16x32_bf16(a, *(const s16x8*)(bp + ct*512), acc[ct], 0, 0, 0);
            }
        }
        if (j > 0) {
            const float* lftM = OUTB(0, i, j-1, 0);
            const unsigned short* Bl = Bsw + 1*MSZ;
            for (int kt = 0; kt < 8; ++kt) {
                s16x8 a = make_afrag(lftM, arow, kt*32 + kk0);
                const unsigned short* bp = Bl + (kt*H + colq)*32 + kk0;
#pragma unroll
                for (int ct = 0; ct < 16; ++ct)
                    acc[ct] = __builtin_amdgcn_mfma_f32_16x16x32_bf16(a, *(const s16x8*)(bp + ct*512), acc[ct], 0, 0, 0);
            }
        }
        const unsigned short* xwp = sxwb + (size_t)i * B * H;
        const unsigned short* ywp = tywb + (size_t)j * B * H;
        float* ox = OUTB(0, i, j, 0);
        float* oy = OUTB(0, i, j, 1);
#pragma unroll
        for (int ct = 0; ct < 16; ++ct) {
            int col = ct*16 + colq;
            float bc = bvec[col];
#pragma unroll
            for (int q = 0; q < 4; ++q) {
                int row = rowq + q;
                float rec = acc[ct][q] + bc;
                ox[row*H + col] = tanh_fast(b2f(xwp[row*H + col]) + rec);
                oy[row*H + col] = tanh_fast(b2f(ywp[row*H + col]) + rec);
            }
        }
    } else {
        const float* hx0 = OUTB(0, i, j, 0);
        const float* hy0 = OUTB(0, i, j, 1);
        const float* topM = (i > 0) ? OUTB(1, i-1, j, 0) : (const float*)0;
        const float* lftM = (j > 0) ? OUTB(1, i, j-1, 0) : (const float*)0;
        const unsigned short* BU1t = Bsw + 2*MSZ;
        const unsigned short* BU1l = Bsw + 3*MSZ;
        const unsigned short* BW1  = Bsw + 4*MSZ;
        float* ox = OUTB(1, i, j, 0);
        float* oy = OUTB(1, i, j, 1);

        for (int halfc = 0; halfc < 2; ++halfc) {
            f32x4 arr[8], axx[8], ayy[8];
#pragma unroll
            for (int t = 0; t < 8; ++t) { arr[t]=(f32x4)(0.f); axx[t]=(f32x4)(0.f); ayy[t]=(f32x4)(0.f); }
            const int bbase = halfc*4096 + colq*32 + kk0;

            for (int kt = 0; kt < 8; ++kt) {
                const int k0 = kt*32 + kk0;
                const int bofs = kt*H*32 + bbase;
                if (topM) {
                    s16x8 a = make_afrag(topM, arow, k0);
#pragma unroll
                    for (int ct = 0; ct < 8; ++ct)
                        arr[ct] = __builtin_amdgcn_mfma_f32_16x16x32_bf16(a, *(const s16x8*)(BU1t + bofs + ct*512), arr[ct], 0, 0, 0);
                }
                if (lftM) {
                    s16x8 a = make_afrag(lftM, arow, k0);
#pragma unroll
                    for (int ct = 0; ct < 8; ++ct)
                        arr[ct] = __builtin_amdgcn_mfma_f32_16x16x32_bf16(a, *(const s16x8*)(BU1l + bofs + ct*512), arr[ct], 0, 0, 0);
                }
                {
                    s16x8 a = make_afrag(hx0, arow, k0);
#pragma unroll
                    for (int ct = 0; ct < 8; ++ct)
                        axx[ct] = __builtin_amdgcn_mfma_f32_16x16x32_bf16(a, *(const s16x8*)(BW1 + bofs + ct*512), axx[ct], 0, 0, 0);
                }
                {
                    s16x8 a = make_afrag(hy0, arow, k0);
#pragma unroll
                    for (int ct = 0; ct < 8; ++ct)
                        ayy[ct] = __builtin_amdgcn_mfma_f32_16x16x32_bf16(a, *(const s16x8*)(BW1 + bofs + ct*512), ayy[ct], 0, 0, 0);
                }
            }
#pragma unroll
            for (int ct = 0; ct < 8; ++ct) {
                int col = halfc*128 + ct*16 + colq;
                float bc = bvec[H + col];
#pragma unroll
                for (int q = 0; q < 4; ++q) {
                    int row = rowq + q;
                    float rec = arr[ct][q] + bc;
                    ox[row*H + col] = tanh_fast(axx[ct][q] + rec);
                    oy[row*H + col] = tanh_fast(ayy[ct][q] + rec);
                }
            }
        }
    }
#undef OUTB
}

// ============================ host launcher ================================
extern "C" void kernel_launch(void* const* d_in, const int* in_sizes, int n_in,
                              void* d_out, int out_size, void* d_ws, size_t ws_size,
                              hipStream_t stream)
{
    const float* src = (const float*)d_in[0];
    const float* trg = (const float*)d_in[1];
    const float* W   = (const float*)d_in[2];
    const float* U   = (const float*)d_in[3];
    const float* b   = (const float*)d_in[4];
    float* out = (float*)d_out;

    const size_t need_stage   = (size_t)5*MSZ*2 + (size_t)2*S*B*H*2;
    const size_t need_persist = need_stage + (size_t)2*S*T*sizeof(int);

    unsigned short* Bsw  = (unsigned short*)d_ws;
    unsigned short* sxwb = Bsw + (size_t)5*MSZ;
    unsigned short* tywb = sxwb + (size_t)S*B*H;
    int* flags = (int*)(tywb + (size_t)S*B*H);

    if (ws_size >= need_persist) {
        prep_kernel<<<(5*MSZ + 255)/256, 256, 0, stream>>>(U, W, Bsw);
        proj0b_kernel<<<2*S*B/ROWSP, 256, 0, stream>>>(src, trg, W, sxwb, tywb);
        zeroflags_kernel<<<(2*S*T + 255)/256, 256, 0, stream>>>(flags, 2*S*T);
        grid_kernel<<<128, 512, 0, stream>>>(Bsw, sxwb, tywb, b, out, flags);
        return;
    }

    // -------- staged fallback --------
    prep_kernel<<<(5*MSZ + 255)/256, 256, 0, stream>>>(U, W, Bsw);
    proj0b_kernel<<<2*S*B/ROWSP, 256, 0, stream>>>(src, trg, W, sxwb, tywb);
    for (int v = 0; v < S + T; ++v) {
        int ilo0 = (v > T-1) ? v-(T-1) : 0, ihi0 = (v < S-1) ? v : S-1;
        int n0 = (v <= S+T-2) ? (ihi0 - ilo0 + 1) : 0;
        if (n0 < 0) n0 = 0;
        int n1 = 0;
        int w1 = v - 1;
        if (w1 >= 0) {
            int ilo1 = (w1 > T-1) ? w1-(T-1) : 0, ihi1 = (w1 < S-1) ? w1 : S-1;
            n1 = ihi1 - ilo1 + 1;
        }
        stage_kernel<<<4*(n0+n1), 64, 0, stream>>>(Bsw, sxwb, tywb, b, out, v);
    }
}

// Round 11
// 672.407 us; speedup vs baseline: 4.4527x; 1.2604x over previous
//
#include <hip/hip_runtime.h>
#include <math.h>

#define S 32
#define T 32
#define B 64
#define H 256
#define MSZ 65536   // elements per swizzled bf16 matrix [8 kt][256 col][32 kk]
#define ROWSP 16

typedef __attribute__((ext_vector_type(8))) short s16x8;
typedef __attribute__((ext_vector_type(4))) float f32x4;

__device__ inline unsigned short f2b(float f){
    unsigned u = __builtin_bit_cast(unsigned, f);
    u += 0x7fffu + ((u >> 16) & 1u);          // RNE
    return (unsigned short)(u >> 16);
}
__device__ inline float b2f(unsigned short s){
    unsigned u = ((unsigned)s) << 16;
    return __builtin_bit_cast(float, u);
}
__device__ inline float tanh_fast(float x){
    float e = __builtin_amdgcn_exp2f(x * 2.8853900817779268f);
    float r = __builtin_amdgcn_rcpf(e + 1.0f);
    return fmaf(-2.0f, r, 1.0f);
}
__device__ inline void waitflag(int* f, int target){
    while (__hip_atomic_load(f, __ATOMIC_RELAXED, __HIP_MEMORY_SCOPE_AGENT) < target)
        __builtin_amdgcn_s_sleep(2);
    (void)__hip_atomic_load(f, __ATOMIC_ACQUIRE, __HIP_MEMORY_SCOPE_AGENT);
}

// ---------------- prep: swizzle U (both depths, top/left) + W[1] to bf16 ----
// Bsw[m][kt][c][kk] = M_m[kt*32+kk][c];  m: 0=U0t 1=U0l 2=U1t 3=U1l 4=W1
__global__ __launch_bounds__(256) void prep_kernel(
    const float* __restrict__ U, const float* __restrict__ W,
    unsigned short* __restrict__ Bsw)
{
    int t = blockIdx.x * 256 + threadIdx.x;
    if (t >= 5 * MSZ) return;
    int m  = t >> 16;
    int r  = t & 65535;
    int kt = r >> 13;
    int r2 = r & 8191;
    int c  = r2 >> 5;
    int kk = r2 & 31;
    int krow = kt * 32 + kk;
    float v;
    if (m < 4){ int d = m >> 1, ope = m & 1; v = U[((size_t)d*2*H + ope*H + krow)*H + c]; }
    else      { v = W[((size_t)H + krow)*H + c]; }   // W[1]
    Bsw[t] = f2b(v);
}

// ---------------- depth-0 projections (bf16 out): sxw = src@W0, tyw = trg@W0
__global__ __launch_bounds__(256) void proj0b_kernel(
    const float* __restrict__ src, const float* __restrict__ trg,
    const float* __restrict__ W0, unsigned short* __restrict__ sxw,
    unsigned short* __restrict__ tyw)
{
    const int c = threadIdx.x;
    int gr0 = blockIdx.x * ROWSP;
    const float* inp; unsigned short* outp; int r0;
    if (gr0 < S * B) { inp = src; outp = sxw; r0 = gr0; }
    else             { inp = trg; outp = tyw; r0 = gr0 - S * B; }

    float acc[ROWSP];
#pragma unroll
    for (int rr = 0; rr < ROWSP; ++rr) acc[rr] = 0.f;
    for (int k = 0; k < H; ++k) {
        float wv = W0[k * H + c];
#pragma unroll
        for (int rr = 0; rr < ROWSP; ++rr)
            acc[rr] = fmaf(inp[(size_t)(r0 + rr) * H + k], wv, acc[rr]);
    }
#pragma unroll
    for (int rr = 0; rr < ROWSP; ++rr)
        outp[(size_t)(r0 + rr) * H + c] = f2b(acc[rr]);
}

__global__ __launch_bounds__(256) void zeroflags_kernel(int* flags, int n){
    int t = blockIdx.x * 256 + threadIdx.x;
    if (t < n) flags[t] = 0;
}

// ---------------- persistent dataflow grid kernel (slack-ordered phases) ---
// 128 blocks: blk 0..63 = depth0 (row=(blk&63)>>1, half=blk&1), 64..127 = d1.
// Same protocol as champion (flags target 2, acquire polls, release publish).
// Per iteration, work is ordered by dependency slack: stale deps (f0 proj,
// left) first, hot dep (top) last -> detect-to-publish R = top phase only.
__global__ __launch_bounds__(512, 2) void grid_kernel(
    const unsigned short* __restrict__ Bsw,
    const unsigned short* __restrict__ sxwb,
    const unsigned short* __restrict__ tywb,
    const float* __restrict__ bvec,
    float* __restrict__ out,
    int* __restrict__ flags)
{
    __shared__ unsigned short Alds[4 * 64 * 128];   // 64 KB
    char* AldsB = (char*)Alds;

    const int blk   = blockIdx.x;
    const int depth = blk >> 6;
    const int i     = (blk & 63) >> 1;
    const int half  = blk & 1;
    const int c0    = half * 128;

    const int tid  = threadIdx.x;
    const int lane = tid & 63;
    const int wv   = tid >> 6;          // wave 0..7, owns 16 cols
    const int colq = lane & 15;
    const int hi   = lane >> 4;
    const int kk0  = hi * 8;
    const int col  = c0 + wv * 16 + colq;
    const int hi16 = hi * 16;
    const int lswz = (colq & 7) << 4;   // A-frag read swizzle (row&7 == colq&7)

    const int row64 = tid >> 3;         // staging row 0..63
    const int k4b   = (tid & 7) * 4;    // staging float4 base within 32
    const int swz   = (row64 & 7) << 4; // staging write swizzle

    int* flag0 = flags;
    int* flag1 = flags + S * T;

    // persistent B fragments in VGPRs
    s16x8 bfT[8], bfL[8], bfW[8];
    {
        const unsigned short* mT = Bsw + (size_t)(depth == 0 ? 0 : 2) * MSZ;
        const unsigned short* mL = Bsw + (size_t)(depth == 0 ? 1 : 3) * MSZ;
        const unsigned short* mW = Bsw + (size_t)4 * MSZ;
#pragma unroll
        for (int kt = 0; kt < 8; ++kt) {
            int o = (kt * H + col) * 32 + kk0;
            bfT[kt] = *(const s16x8*)(mT + o);
            bfL[kt] = *(const s16x8*)(mL + o);
            bfW[kt] = *(const s16x8*)(mW + o);
        }
    }

    const size_t CH = (size_t)B * H;
#define OPTR(dd,ii,jj,ch) (out + ((((size_t)(dd)*S + (ii))*T + (jj))*2 + (ch)) * CH)

#define LOADOP(OP, SP, KC) do { \
    const float* _p = (SP) + (size_t)row64 * H + (KC)*128 + k4b*4; \
    L[(OP)*4+0] = *(const float4*)(_p); \
    L[(OP)*4+1] = *(const float4*)(_p + 4); \
    L[(OP)*4+2] = *(const float4*)(_p + 8); \
    L[(OP)*4+3] = *(const float4*)(_p + 12); \
} while(0)

#define WRITEOP(OP) do { \
    _Pragma("unroll") \
    for (int _l = 0; _l < 4; ++_l) { \
        float4 _v = L[(OP)*4+_l]; \
        uint2 _u; \
        _u.x = f2b(_v.x) | ((unsigned)f2b(_v.y) << 16); \
        _u.y = f2b(_v.z) | ((unsigned)f2b(_v.w) << 16); \
        *(uint2*)(AldsB + (OP)*16384 + row64*256 + (((k4b+_l)*8) ^ swz)) = _u; \
    } \
} while(0)

#define AFRAG(OP, RT, KTL) (*(const s16x8*)(AldsB + (OP)*16384 + ((RT)*16 + colq)*256 + ((((KTL)*64) + hi16) ^ lswz)))

// one staged operand: poll flag (if FP), stage chunk0, MFMA c0 under c1 load,
// MFMA c1; accumulates ACC += A_op x BF
#define OPPHASE(OP, FP, TGT, SPTR, BF, ACC) do { \
    if ((FP)) { if (tid == 0) waitflag((FP), (TGT)); } \
    __syncthreads(); \
    const float* _sp = (SPTR); \
    LOADOP(OP, _sp, 0); \
    WRITEOP(OP); \
    __syncthreads(); \
    LOADOP(OP, _sp, 1); \
    _Pragma("unroll") \
    for (int _ktl = 0; _ktl < 4; ++_ktl) \
        _Pragma("unroll") \
        for (int _rt = 0; _rt < 4; ++_rt) \
            ACC[_rt] = __builtin_amdgcn_mfma_f32_16x16x32_bf16(AFRAG(OP,_rt,_ktl), BF[_ktl], ACC[_rt], 0, 0, 0); \
    __syncthreads(); \
    WRITEOP(OP); \
    __syncthreads(); \
    _Pragma("unroll") \
    for (int _ktl = 0; _ktl < 4; ++_ktl) \
        _Pragma("unroll") \
        for (int _rt = 0; _rt < 4; ++_rt) \
            ACC[_rt] = __builtin_amdgcn_mfma_f32_16x16x32_bf16(AFRAG(OP,_rt,_ktl), BF[4+_ktl], ACC[_rt], 0, 0, 0); \
} while(0)

    if (depth == 0) {
        // xw is j-invariant: registers once
        unsigned short xwr[16];
        {
            const unsigned short* xwp = sxwb + (size_t)i * B * H;
#pragma unroll
            for (int rt = 0; rt < 4; ++rt)
#pragma unroll
                for (int q = 0; q < 4; ++q)
                    xwr[rt*4+q] = xwp[(size_t)(rt*16 + hi*4 + q) * H + col];
        }

        for (int j = 0; j < T; ++j) {
            // yw: issue loads before any polling (latency hides under phases)
            unsigned short ywr[16];
            {
                const unsigned short* ywp = tywb + (size_t)j * B * H;
#pragma unroll
                for (int rt = 0; rt < 4; ++rt)
#pragma unroll
                    for (int q = 0; q < 4; ++q)
                        ywr[rt*4+q] = ywp[(size_t)(rt*16 + hi*4 + q) * H + col];
            }

            f32x4 acc[4];
#pragma unroll
            for (int rt = 0; rt < 4; ++rt) acc[rt] = (f32x4)(0.f);
            float4 L[16];

            // left phase first (flag is one full period stale -> instant)
            if (j > 0)
                OPPHASE(1, &flag0[i*T + (j-1)], 2, OPTR(0, i, j-1, 0), bfL, acc);
            // top phase last (the hot dependency)
            if (i > 0)
                OPPHASE(0, &flag0[(i-1)*T + j], 2, OPTR(0, i-1, j, 0), bfT, acc);

            float* ox = OPTR(0, i, j, 0);
            float* oy = OPTR(0, i, j, 1);
            const float bc = bvec[col];
#pragma unroll
            for (int rt = 0; rt < 4; ++rt)
#pragma unroll
                for (int q = 0; q < 4; ++q) {
                    int idx = rt*4 + q;
                    int row = rt*16 + hi*4 + q;
                    float rec = acc[rt][q] + bc;
                    float hx = tanh_fast(b2f(xwr[idx]) + rec);
                    float hy = tanh_fast(b2f(ywr[idx]) + rec);
                    __hip_atomic_store(&ox[row*H + col], hx, __ATOMIC_RELAXED, __HIP_MEMORY_SCOPE_AGENT);
                    __hip_atomic_store(&oy[row*H + col], hy, __ATOMIC_RELAXED, __HIP_MEMORY_SCOPE_AGENT);
                }

            asm volatile("s_waitcnt vmcnt(0)" ::: "memory");
            __syncthreads();
            if (tid == 0)
                __hip_atomic_fetch_add(&flag0[i*T + j], 1, __ATOMIC_RELEASE, __HIP_MEMORY_SCOPE_AGENT);
        }
    } else {
        for (int j = 0; j < T; ++j) {
            f32x4 ar[4], ax[4], ay[4];
#pragma unroll
            for (int rt = 0; rt < 4; ++rt){ ar[rt] = (f32x4)(0.f); ax[rt] = (f32x4)(0.f); ay[rt] = (f32x4)(0.f); }
            float4 L[16];

            // phase P: projections from hx0/hy0 (f0 is ~2 periods stale)
            {
                if (tid == 0) waitflag(&flag0[i*T + j], 2);
                __syncthreads();
                const float* sHx0 = OPTR(0, i, j, 0);
                const float* sHy0 = OPTR(0, i, j, 1);
                LOADOP(2, sHx0, 0); LOADOP(3, sHy0, 0);
                WRITEOP(2); WRITEOP(3);
                __syncthreads();
                LOADOP(2, sHx0, 1); LOADOP(3, sHy0, 1);
#pragma unroll
                for (int ktl = 0; ktl < 4; ++ktl)
#pragma unroll
                    for (int rt = 0; rt < 4; ++rt) {
                        ax[rt] = __builtin_amdgcn_mfma_f32_16x16x32_bf16(AFRAG(2,rt,ktl), bfW[ktl], ax[rt], 0, 0, 0);
                        ay[rt] = __builtin_amdgcn_mfma_f32_16x16x32_bf16(AFRAG(3,rt,ktl), bfW[ktl], ay[rt], 0, 0, 0);
                    }
                __syncthreads();
                WRITEOP(2); WRITEOP(3);
                __syncthreads();
#pragma unroll
                for (int ktl = 0; ktl < 4; ++ktl)
#pragma unroll
                    for (int rt = 0; rt < 4; ++rt) {
                        ax[rt] = __builtin_amdgcn_mfma_f32_16x16x32_bf16(AFRAG(2,rt,ktl), bfW[4+ktl], ax[rt], 0, 0, 0);
                        ay[rt] = __builtin_amdgcn_mfma_f32_16x16x32_bf16(AFRAG(3,rt,ktl), bfW[4+ktl], ay[rt], 0, 0, 0);
                    }
            }

            // left phase (stale), then top phase (hot)
            if (j > 0)
                OPPHASE(1, &flag1[i*T + (j-1)], 2, OPTR(1, i, j-1, 0), bfL, ar);
            if (i > 0)
                OPPHASE(0, &flag1[(i-1)*T + j], 2, OPTR(1, i-1, j, 0), bfT, ar);

            // epilogue: hx1 (consumed) -> drain -> publish; hy1 (dead) after
            float recs[16];
            float* ox = OPTR(1, i, j, 0);
            const float bc = bvec[H + col];
#pragma unroll
            for (int rt = 0; rt < 4; ++rt)
#pragma unroll
                for (int q = 0; q < 4; ++q) {
                    int idx = rt*4 + q;
                    int row = rt*16 + hi*4 + q;
                    float rec = ar[rt][q] + bc;
                    recs[idx] = rec;
                    float hx = tanh_fast(ax[rt][q] + rec);
                    __hip_atomic_store(&ox[row*H + col], hx, __ATOMIC_RELAXED, __HIP_MEMORY_SCOPE_AGENT);
                }
            asm volatile("s_waitcnt vmcnt(0)" ::: "memory");
            __syncthreads();
            if (tid == 0)
                __hip_atomic_fetch_add(&flag1[i*T + j], 1, __ATOMIC_RELEASE, __HIP_MEMORY_SCOPE_AGENT);

            float* oy = OPTR(1, i, j, 1);
#pragma unroll
            for (int rt = 0; rt < 4; ++rt)
#pragma unroll
                for (int q = 0; q < 4; ++q) {
                    int idx = rt*4 + q;
                    int row = rt*16 + hi*4 + q;
                    float hy = tanh_fast(ay[rt][q] + recs[idx]);
                    __hip_atomic_store(&oy[row*H + col], hy, __ATOMIC_RELAXED, __HIP_MEMORY_SCOPE_AGENT);
                }
        }
    }
#undef OPTR
#undef LOADOP
#undef WRITEOP
#undef AFRAG
#undef OPPHASE
}

// =================== staged fallback (round-2 structure) ===================
__device__ inline s16x8 make_afrag(const float* __restrict__ M, int arow, int k0){
    const float* p = M + arow * H + k0;
    float4 x = *(const float4*)(p);
    float4 y = *(const float4*)(p + 4);
    s16x8 r;
    r[0]=(short)f2b(x.x); r[1]=(short)f2b(x.y); r[2]=(short)f2b(x.z); r[3]=(short)f2b(x.w);
    r[4]=(short)f2b(y.x); r[5]=(short)f2b(y.y); r[6]=(short)f2b(y.z); r[7]=(short)f2b(y.w);
    return r;
}

__global__ __launch_bounds__(64) void stage_kernel(
    const unsigned short* __restrict__ Bsw,
    const unsigned short* __restrict__ sxwb,
    const unsigned short* __restrict__ tywb,
    const float* __restrict__ bvec,
    float* __restrict__ out, int v)
{
    const int lane = threadIdx.x;
    const int cellid = blockIdx.x >> 2;
    const int stripe = blockIdx.x & 3;

    int ilo0 = (v > T-1) ? v-(T-1) : 0, ihi0 = (v < S-1) ? v : S-1;
    int n0 = (v <= S+T-2) ? (ihi0 - ilo0 + 1) : 0;
    if (n0 < 0) n0 = 0;
    int w1 = v - 1;
    int ilo1 = (w1 > T-1) ? w1-(T-1) : 0;

    int d, i, j;
    if (cellid < n0) { d = 0; i = ilo0 + cellid; j = v - i; }
    else             { d = 1; int q = cellid - n0; i = ilo1 + q; j = w1 - i; }

    const int r0   = stripe * 16;
    const int arow = r0 + (lane & 15);
    const int kk0  = (lane >> 4) * 8;
    const int colq = lane & 15;
    const int rowq = r0 + ((lane >> 4) << 2);

#define OUTB(dd,ii,jj,ch) (out + ((((size_t)(dd)*S + (ii))*T + (jj))*2 + (ch)) * (size_t)(B*H))

    if (d == 0) {
        f32x4 acc[16];
#pragma unroll
        for (int t = 0; t < 16; ++t) acc[t] = (f32x4)(0.f);
        if (i > 0) {
            const float* topM = OUTB(0, i-1, j, 0);
            const unsigned short* Bt = Bsw + 0*MSZ;
            for (int kt = 0; kt < 8; ++kt) {
                s16x8 a = make_afrag(topM, arow, kt*32 + kk0);
                const unsigned short* bp = Bt + (kt*H + colq)*32 + kk0;
#pragma unroll
                for (int ct = 0; ct < 16; ++ct)
                    acc[ct] = __builtin_amdgcn_mfma_f32_16x16x32_bf16(a, *(const s16x8*)(bp + ct*512), acc[ct], 0, 0, 0);
            }
        }
        if (j > 0) {
            const float* lftM = OUTB(0, i, j-1, 0);
            const unsigned short* Bl = Bsw + 1*MSZ;
            for (int kt = 0; kt < 8; ++kt) {
                s16x8 a = make_afrag(lftM, arow, kt*32 + kk0);
                const unsigned short* bp = Bl + (kt*H + colq)*32 + kk0;
#pragma unroll
                for (int ct = 0; ct < 16; ++ct)
                    acc[ct] = __builtin_amdgcn_mfma_f32_16x16x32_bf16(a, *(const s16x8*)(bp + ct*512), acc[ct], 0, 0, 0);
            }
        }
        const unsigned short* xwp = sxwb + (size_t)i * B * H;
        const unsigned short* ywp = tywb + (size_t)j * B * H;
        float* ox = OUTB(0, i, j, 0);
        float* oy = OUTB(0, i, j, 1);
#pragma unroll
        for (int ct = 0; ct < 16; ++ct) {
            int col = ct*16 + colq;
            float bc = bvec[col];
#pragma unroll
            for (int q = 0; q < 4; ++q) {
                int row = rowq + q;
                float rec = acc[ct][q] + bc;
                ox[row*H + col] = tanh_fast(b2f(xwp[row*H + col]) + rec);
                oy[row*H + col] = tanh_fast(b2f(ywp[row*H + col]) + rec);
            }
        }
    } else {
        const float* hx0 = OUTB(0, i, j, 0);
        const float* hy0 = OUTB(0, i, j, 1);
        const float* topM = (i > 0) ? OUTB(1, i-1, j, 0) : (const float*)0;
        const float* lftM = (j > 0) ? OUTB(1, i, j-1, 0) : (const float*)0;
        const unsigned short* BU1t = Bsw + 2*MSZ;
        const unsigned short* BU1l = Bsw + 3*MSZ;
        const unsigned short* BW1  = Bsw + 4*MSZ;
        float* ox = OUTB(1, i, j, 0);
        float* oy = OUTB(1, i, j, 1);

        for (int halfc = 0; halfc < 2; ++halfc) {
            f32x4 arr[8], axx[8], ayy[8];
#pragma unroll
            for (int t = 0; t < 8; ++t) { arr[t]=(f32x4)(0.f); axx[t]=(f32x4)(0.f); ayy[t]=(f32x4)(0.f); }
            const int bbase = halfc*4096 + colq*32 + kk0;

            for (int kt = 0; kt < 8; ++kt) {
                const int k0 = kt*32 + kk0;
                const int bofs = kt*H*32 + bbase;
                if (topM) {
                    s16x8 a = make_afrag(topM, arow, k0);
#pragma unroll
                    for (int ct = 0; ct < 8; ++ct)
                        arr[ct] = __builtin_amdgcn_mfma_f32_16x16x32_bf16(a, *(const s16x8*)(BU1t + bofs + ct*512), arr[ct], 0, 0, 0);
                }
                if (lftM) {
                    s16x8 a = make_afrag(lftM, arow, k0);
#pragma unroll
                    for (int ct = 0; ct < 8; ++ct)
                        arr[ct] = __builtin_amdgcn_mfma_f32_16x16x32_bf16(a, *(const s16x8*)(BU1l + bofs + ct*512), arr[ct], 0, 0, 0);
                }
                {
                    s16x8 a = make_afrag(hx0, arow, k0);
#pragma unroll
                    for (int ct = 0; ct < 8; ++ct)
                        axx[ct] = __builtin_amdgcn_mfma_f32_16x16x32_bf16(a, *(const s16x8*)(BW1 + bofs + ct*512), axx[ct], 0, 0, 0);
                }
                {
                    s16x8 a = make_afrag(hy0, arow, k0);
#pragma unroll
                    for (int ct = 0; ct < 8; ++ct)
                        ayy[ct] = __builtin_amdgcn_mfma_f32_16x16x32_bf16(a, *(const s16x8*)(BW1 + bofs + ct*512), ayy[ct], 0, 0, 0);
                }
            }
#pragma unroll
            for (int ct = 0; ct < 8; ++ct) {
                int col = halfc*128 + ct*16 + colq;
                float bc = bvec[H + col];
#pragma unroll
                for (int q = 0; q < 4; ++q) {
                    int row = rowq + q;
                    float rec = arr[ct][q] + bc;
                    ox[row*H + col] = tanh_fast(axx[ct][q] + rec);
                    oy[row*H + col] = tanh_fast(ayy[ct][q] + rec);
                }
            }
        }
    }
#undef OUTB
}

// ============================ host launcher ================================
extern "C" void kernel_launch(void* const* d_in, const int* in_sizes, int n_in,
                              void* d_out, int out_size, void* d_ws, size_t ws_size,
                              hipStream_t stream)
{
    const float* src = (const float*)d_in[0];
    const float* trg = (const float*)d_in[1];
    const float* W   = (const float*)d_in[2];
    const float* U   = (const float*)d_in[3];
    const float* b   = (const float*)d_in[4];
    float* out = (float*)d_out;

    const size_t need_stage   = (size_t)5*MSZ*2 + (size_t)2*S*B*H*2;
    const size_t need_persist = need_stage + (size_t)2*S*T*sizeof(int);

    unsigned short* Bsw  = (unsigned short*)d_ws;
    unsigned short* sxwb = Bsw + (size_t)5*MSZ;
    unsigned short* tywb = sxwb + (size_t)S*B*H;
    int* flags = (int*)(tywb + (size_t)S*B*H);

    if (ws_size >= need_persist) {
        prep_kernel<<<(5*MSZ + 255)/256, 256, 0, stream>>>(U, W, Bsw);
        proj0b_kernel<<<2*S*B/ROWSP, 256, 0, stream>>>(src, trg, W, sxwb, tywb);
        zeroflags_kernel<<<(2*S*T + 255)/256, 256, 0, stream>>>(flags, 2*S*T);
        grid_kernel<<<128, 512, 0, stream>>>(Bsw, sxwb, tywb, b, out, flags);
        return;
    }

    // -------- staged fallback --------
    prep_kernel<<<(5*MSZ + 255)/256, 256, 0, stream>>>(U, W, Bsw);
    proj0b_kernel<<<2*S*B/ROWSP, 256, 0, stream>>>(src, trg, W, sxwb, tywb);
    for (int v = 0; v < S + T; ++v) {
        int ilo0 = (v > T-1) ? v-(T-1) : 0, ihi0 = (v < S-1) ? v : S-1;
        int n0 = (v <= S+T-2) ? (ihi0 - ilo0 + 1) : 0;
        if (n0 < 0) n0 = 0;
        int n1 = 0;
        int w1 = v - 1;
        if (w1 >= 0) {
            int ilo1 = (w1 > T-1) ? w1-(T-1) : 0, ihi1 = (w1 < S-1) ? w1 : S-1;
            n1 = ihi1 - ilo1 + 1;
        }
        stage_kernel<<<4*(n0+n1), 64, 0, stream>>>(Bsw, sxwb, tywb, b, out, v);
    }
}

// Round 12
// 641.311 us; speedup vs baseline: 4.6686x; 1.0485x over previous
//
#include <hip/hip_runtime.h>
#include <math.h>

#define S 32
#define T 32
#define B 64
#define H 256
#define MSZ 65536   // elements per swizzled bf16 matrix [8 kt][256 col][32 kk]
#define ROWSP 16

typedef __attribute__((ext_vector_type(8))) short s16x8;
typedef __attribute__((ext_vector_type(4))) float f32x4;

__device__ inline unsigned short f2b(float f){
    unsigned u = __builtin_bit_cast(unsigned, f);
    u += 0x7fffu + ((u >> 16) & 1u);          // RNE
    return (unsigned short)(u >> 16);
}
__device__ inline float b2f(unsigned short s){
    unsigned u = ((unsigned)s) << 16;
    return __builtin_bit_cast(float, u);
}
__device__ inline float tanh_fast(float x){
    float e = __builtin_amdgcn_exp2f(x * 2.8853900817779268f);
    float r = __builtin_amdgcn_rcpf(e + 1.0f);
    return fmaf(-2.0f, r, 1.0f);
}
__device__ inline void waitflag(int* f, int target){
    while (__hip_atomic_load(f, __ATOMIC_RELAXED, __HIP_MEMORY_SCOPE_AGENT) < target)
        __builtin_amdgcn_s_sleep(2);
    (void)__hip_atomic_load(f, __ATOMIC_ACQUIRE, __HIP_MEMORY_SCOPE_AGENT);
}

// ---------------- prep: swizzle U (both depths, top/left) + W[1] to bf16 ----
// Bsw[m][kt][c][kk] = M_m[kt*32+kk][c];  m: 0=U0t 1=U0l 2=U1t 3=U1l 4=W1
__global__ __launch_bounds__(256) void prep_kernel(
    const float* __restrict__ U, const float* __restrict__ W,
    unsigned short* __restrict__ Bsw)
{
    int t = blockIdx.x * 256 + threadIdx.x;
    if (t >= 5 * MSZ) return;
    int m  = t >> 16;
    int r  = t & 65535;
    int kt = r >> 13;
    int r2 = r & 8191;
    int c  = r2 >> 5;
    int kk = r2 & 31;
    int krow = kt * 32 + kk;
    float v;
    if (m < 4){ int d = m >> 1, ope = m & 1; v = U[((size_t)d*2*H + ope*H + krow)*H + c]; }
    else      { v = W[((size_t)H + krow)*H + c]; }   // W[1]
    Bsw[t] = f2b(v);
}

// ---------------- depth-0 projections (bf16 out): sxw = src@W0, tyw = trg@W0
__global__ __launch_bounds__(256) void proj0b_kernel(
    const float* __restrict__ src, const float* __restrict__ trg,
    const float* __restrict__ W0, unsigned short* __restrict__ sxw,
    unsigned short* __restrict__ tyw)
{
    const int c = threadIdx.x;
    int gr0 = blockIdx.x * ROWSP;
    const float* inp; unsigned short* outp; int r0;
    if (gr0 < S * B) { inp = src; outp = sxw; r0 = gr0; }
    else             { inp = trg; outp = tyw; r0 = gr0 - S * B; }

    float acc[ROWSP];
#pragma unroll
    for (int rr = 0; rr < ROWSP; ++rr) acc[rr] = 0.f;
    for (int k = 0; k < H; ++k) {
        float wv = W0[k * H + c];
#pragma unroll
        for (int rr = 0; rr < ROWSP; ++rr)
            acc[rr] = fmaf(inp[(size_t)(r0 + rr) * H + k], wv, acc[rr]);
    }
#pragma unroll
    for (int rr = 0; rr < ROWSP; ++rr)
        outp[(size_t)(r0 + rr) * H + c] = f2b(acc[rr]);
}

__global__ __launch_bounds__(256) void zeroflags_kernel(int* flags, int n){
    int t = blockIdx.x * 256 + threadIdx.x;
    if (t < n) flags[t] = 0;
}

// ---------------- persistent dataflow grid kernel (R11 + proj offload) -----
// 192 blocks: 0..63 d0 (row=(blk&63)>>1, half=blk&1); 64..127 d1; 128..191
// proj. Proj blocks (no self-chain): poll f0 -> px=hx0@W1, py=hy0@W1 stored
// into d1's output slots -> publish gg. d1 reads px/py as registers.
__global__ __launch_bounds__(512, 2) void grid_kernel(
    const unsigned short* __restrict__ Bsw,
    const unsigned short* __restrict__ sxwb,
    const unsigned short* __restrict__ tywb,
    const float* __restrict__ bvec,
    float* __restrict__ out,
    int* __restrict__ flags)
{
    __shared__ unsigned short Alds[4 * 64 * 128];   // 64 KB
    char* AldsB = (char*)Alds;

    const int blk   = blockIdx.x;
    const int btyp  = blk >> 6;         // 0=d0, 1=d1, 2=proj
    const int i     = (blk & 63) >> 1;
    const int half  = blk & 1;
    const int c0    = half * 128;

    const int tid  = threadIdx.x;
    const int lane = tid & 63;
    const int wv   = tid >> 6;          // wave 0..7, owns 16 cols
    const int colq = lane & 15;
    const int hi   = lane >> 4;
    const int kk0  = hi * 8;
    const int col  = c0 + wv * 16 + colq;
    const int hi16 = hi * 16;
    const int lswz = (colq & 7) << 4;   // A-frag read swizzle (row&7 == colq&7)

    const int row64 = tid >> 3;         // staging row 0..63
    const int k4b   = (tid & 7) * 4;    // staging float4 base within 32
    const int swz   = (row64 & 7) << 4; // staging write swizzle

    int* flag0 = flags;
    int* flag1 = flags + S * T;
    int* flagg = flags + 2 * S * T;

    const size_t CH = (size_t)B * H;
#define OPTR(dd,ii,jj,ch) (out + ((((size_t)(dd)*S + (ii))*T + (jj))*2 + (ch)) * CH)

#define LOADOP(OP, SP, KC) do { \
    const float* _p = (SP) + (size_t)row64 * H + (KC)*128 + k4b*4; \
    L[(OP)*4+0] = *(const float4*)(_p); \
    L[(OP)*4+1] = *(const float4*)(_p + 4); \
    L[(OP)*4+2] = *(const float4*)(_p + 8); \
    L[(OP)*4+3] = *(const float4*)(_p + 12); \
} while(0)

#define WRITEOP(OP) do { \
    _Pragma("unroll") \
    for (int _l = 0; _l < 4; ++_l) { \
        float4 _v = L[(OP)*4+_l]; \
        uint2 _u; \
        _u.x = f2b(_v.x) | ((unsigned)f2b(_v.y) << 16); \
        _u.y = f2b(_v.z) | ((unsigned)f2b(_v.w) << 16); \
        *(uint2*)(AldsB + (OP)*16384 + row64*256 + (((k4b+_l)*8) ^ swz)) = _u; \
    } \
} while(0)

#define AFRAG(OP, RT, KTL) (*(const s16x8*)(AldsB + (OP)*16384 + ((RT)*16 + colq)*256 + ((((KTL)*64) + hi16) ^ lswz)))

// one staged operand: poll flag (if FP), stage chunk0, MFMA c0 under c1 load,
// MFMA c1; accumulates ACC += A_op x BF
#define OPPHASE(OP, FP, TGT, SPTR, BF, ACC) do { \
    if ((FP)) { if (tid == 0) waitflag((FP), (TGT)); } \
    __syncthreads(); \
    const float* _sp = (SPTR); \
    LOADOP(OP, _sp, 0); \
    WRITEOP(OP); \
    __syncthreads(); \
    LOADOP(OP, _sp, 1); \
    _Pragma("unroll") \
    for (int _ktl = 0; _ktl < 4; ++_ktl) \
        _Pragma("unroll") \
        for (int _rt = 0; _rt < 4; ++_rt) \
            ACC[_rt] = __builtin_amdgcn_mfma_f32_16x16x32_bf16(AFRAG(OP,_rt,_ktl), BF[_ktl], ACC[_rt], 0, 0, 0); \
    __syncthreads(); \
    WRITEOP(OP); \
    __syncthreads(); \
    _Pragma("unroll") \
    for (int _ktl = 0; _ktl < 4; ++_ktl) \
        _Pragma("unroll") \
        for (int _rt = 0; _rt < 4; ++_rt) \
            ACC[_rt] = __builtin_amdgcn_mfma_f32_16x16x32_bf16(AFRAG(OP,_rt,_ktl), BF[4+_ktl], ACC[_rt], 0, 0, 0); \
} while(0)

    if (btyp == 0) {
        // ===================== depth-0 =====================
        s16x8 bfT[8], bfL[8];
#pragma unroll
        for (int kt = 0; kt < 8; ++kt) {
            int o = (kt * H + col) * 32 + kk0;
            bfT[kt] = *(const s16x8*)(Bsw + o);
            bfL[kt] = *(const s16x8*)(Bsw + (size_t)MSZ + o);
        }
        // xw is j-invariant: registers once
        unsigned short xwr[16];
        {
            const unsigned short* xwp = sxwb + (size_t)i * B * H;
#pragma unroll
            for (int rt = 0; rt < 4; ++rt)
#pragma unroll
                for (int q = 0; q < 4; ++q)
                    xwr[rt*4+q] = xwp[(size_t)(rt*16 + hi*4 + q) * H + col];
        }

        for (int j = 0; j < T; ++j) {
            // yw: issue loads before any polling
            unsigned short ywr[16];
            {
                const unsigned short* ywp = tywb + (size_t)j * B * H;
#pragma unroll
                for (int rt = 0; rt < 4; ++rt)
#pragma unroll
                    for (int q = 0; q < 4; ++q)
                        ywr[rt*4+q] = ywp[(size_t)(rt*16 + hi*4 + q) * H + col];
            }

            f32x4 acc[4];
#pragma unroll
            for (int rt = 0; rt < 4; ++rt) acc[rt] = (f32x4)(0.f);
            float4 L[16];

            if (j > 0)
                OPPHASE(1, &flag0[i*T + (j-1)], 2, OPTR(0, i, j-1, 0), bfL, acc);
            if (i > 0)
                OPPHASE(0, &flag0[(i-1)*T + j], 2, OPTR(0, i-1, j, 0), bfT, acc);

            float* ox = OPTR(0, i, j, 0);
            float* oy = OPTR(0, i, j, 1);
            const float bc = bvec[col];
#pragma unroll
            for (int rt = 0; rt < 4; ++rt)
#pragma unroll
                for (int q = 0; q < 4; ++q) {
                    int idx = rt*4 + q;
                    int row = rt*16 + hi*4 + q;
                    float rec = acc[rt][q] + bc;
                    float hx = tanh_fast(b2f(xwr[idx]) + rec);
                    float hy = tanh_fast(b2f(ywr[idx]) + rec);
                    __hip_atomic_store(&ox[row*H + col], hx, __ATOMIC_RELAXED, __HIP_MEMORY_SCOPE_AGENT);
                    __hip_atomic_store(&oy[row*H + col], hy, __ATOMIC_RELAXED, __HIP_MEMORY_SCOPE_AGENT);
                }

            asm volatile("s_waitcnt vmcnt(0)" ::: "memory");
            __syncthreads();
            if (tid == 0)
                __hip_atomic_fetch_add(&flag0[i*T + j], 1, __ATOMIC_RELEASE, __HIP_MEMORY_SCOPE_AGENT);
        }
    } else if (btyp == 1) {
        // ===================== depth-1 =====================
        s16x8 bfT[8], bfL[8];
#pragma unroll
        for (int kt = 0; kt < 8; ++kt) {
            int o = (kt * H + col) * 32 + kk0;
            bfT[kt] = *(const s16x8*)(Bsw + (size_t)2*MSZ + o);
            bfL[kt] = *(const s16x8*)(Bsw + (size_t)3*MSZ + o);
        }

        for (int j = 0; j < T; ++j) {
            // poll gg (stale: proj shadows d0, which runs ahead of us), then
            // issue px/py register loads early — latency hides under phases
            if (tid == 0) waitflag(&flagg[i*T + j], 2);
            __syncthreads();
            float pxr[16], pyr[16];
            {
                const float* p0s = OPTR(1, i, j, 0);
                const float* p1s = OPTR(1, i, j, 1);
#pragma unroll
                for (int rt = 0; rt < 4; ++rt)
#pragma unroll
                    for (int q = 0; q < 4; ++q) {
                        int idx = rt*4 + q;
                        int row = rt*16 + hi*4 + q;
                        pxr[idx] = p0s[row*H + col];
                        pyr[idx] = p1s[row*H + col];
                    }
            }

            f32x4 ar[4];
#pragma unroll
            for (int rt = 0; rt < 4; ++rt) ar[rt] = (f32x4)(0.f);
            float4 L[16];

            if (j > 0)
                OPPHASE(1, &flag1[i*T + (j-1)], 2, OPTR(1, i, j-1, 0), bfL, ar);
            if (i > 0)
                OPPHASE(0, &flag1[(i-1)*T + j], 2, OPTR(1, i-1, j, 0), bfT, ar);

            // epilogue: hx1 (consumed) -> drain -> publish; hy1 (dead) after
            float recs[16];
            float* ox = OPTR(1, i, j, 0);
            const float bc = bvec[H + col];
#pragma unroll
            for (int rt = 0; rt < 4; ++rt)
#pragma unroll
                for (int q = 0; q < 4; ++q) {
                    int idx = rt*4 + q;
                    int row = rt*16 + hi*4 + q;
                    float rec = ar[rt][q] + bc;
                    recs[idx] = rec;
                    float hx = tanh_fast(pxr[idx] + rec);
                    __hip_atomic_store(&ox[row*H + col], hx, __ATOMIC_RELAXED, __HIP_MEMORY_SCOPE_AGENT);
                }
            asm volatile("s_waitcnt vmcnt(0)" ::: "memory");
            __syncthreads();
            if (tid == 0)
                __hip_atomic_fetch_add(&flag1[i*T + j], 1, __ATOMIC_RELEASE, __HIP_MEMORY_SCOPE_AGENT);

            float* oy = OPTR(1, i, j, 1);
#pragma unroll
            for (int rt = 0; rt < 4; ++rt)
#pragma unroll
                for (int q = 0; q < 4; ++q) {
                    int idx = rt*4 + q;
                    int row = rt*16 + hi*4 + q;
                    float hy = tanh_fast(pyr[idx] + recs[idx]);
                    __hip_atomic_store(&oy[row*H + col], hy, __ATOMIC_RELAXED, __HIP_MEMORY_SCOPE_AGENT);
                }
        }
    } else {
        // ===================== projection (no self-chain) =====================
        s16x8 bfW[8];
#pragma unroll
        for (int kt = 0; kt < 8; ++kt)
            bfW[kt] = *(const s16x8*)(Bsw + (size_t)4*MSZ + (kt * H + col) * 32 + kk0);

        for (int j = 0; j < T; ++j) {
            if (tid == 0) waitflag(&flag0[i*T + j], 2);
            __syncthreads();

            f32x4 px[4], py[4];
#pragma unroll
            for (int rt = 0; rt < 4; ++rt) { px[rt] = (f32x4)(0.f); py[rt] = (f32x4)(0.f); }
            float4 L[16];

            const float* sHx0 = OPTR(0, i, j, 0);
            const float* sHy0 = OPTR(0, i, j, 1);
            LOADOP(2, sHx0, 0); LOADOP(3, sHy0, 0);
            WRITEOP(2); WRITEOP(3);
            __syncthreads();
            LOADOP(2, sHx0, 1); LOADOP(3, sHy0, 1);
#pragma unroll
            for (int ktl = 0; ktl < 4; ++ktl)
#pragma unroll
                for (int rt = 0; rt < 4; ++rt) {
                    px[rt] = __builtin_amdgcn_mfma_f32_16x16x32_bf16(AFRAG(2,rt,ktl), bfW[ktl], px[rt], 0, 0, 0);
                    py[rt] = __builtin_amdgcn_mfma_f32_16x16x32_bf16(AFRAG(3,rt,ktl), bfW[ktl], py[rt], 0, 0, 0);
                }
            __syncthreads();
            WRITEOP(2); WRITEOP(3);
            __syncthreads();
#pragma unroll
            for (int ktl = 0; ktl < 4; ++ktl)
#pragma unroll
                for (int rt = 0; rt < 4; ++rt) {
                    px[rt] = __builtin_amdgcn_mfma_f32_16x16x32_bf16(AFRAG(2,rt,ktl), bfW[4+ktl], px[rt], 0, 0, 0);
                    py[rt] = __builtin_amdgcn_mfma_f32_16x16x32_bf16(AFRAG(3,rt,ktl), bfW[4+ktl], py[rt], 0, 0, 0);
                }

            float* p0 = OPTR(1, i, j, 0);
            float* p1 = OPTR(1, i, j, 1);
#pragma unroll
            for (int rt = 0; rt < 4; ++rt)
#pragma unroll
                for (int q = 0; q < 4; ++q) {
                    int row = rt*16 + hi*4 + q;
                    __hip_atomic_store(&p0[row*H + col], px[rt][q], __ATOMIC_RELAXED, __HIP_MEMORY_SCOPE_AGENT);
                    __hip_atomic_store(&p1[row*H + col], py[rt][q], __ATOMIC_RELAXED, __HIP_MEMORY_SCOPE_AGENT);
                }
            asm volatile("s_waitcnt vmcnt(0)" ::: "memory");
            __syncthreads();
            if (tid == 0)
                __hip_atomic_fetch_add(&flagg[i*T + j], 1, __ATOMIC_RELEASE, __HIP_MEMORY_SCOPE_AGENT);
        }
    }
#undef OPTR
#undef LOADOP
#undef WRITEOP
#undef AFRAG
#undef OPPHASE
}

// =================== staged fallback (round-2 structure) ===================
__device__ inline s16x8 make_afrag(const float* __restrict__ M, int arow, int k0){
    const float* p = M + arow * H + k0;
    float4 x = *(const float4*)(p);
    float4 y = *(const float4*)(p + 4);
    s16x8 r;
    r[0]=(short)f2b(x.x); r[1]=(short)f2b(x.y); r[2]=(short)f2b(x.z); r[3]=(short)f2b(x.w);
    r[4]=(short)f2b(y.x); r[5]=(short)f2b(y.y); r[6]=(short)f2b(y.z); r[7]=(short)f2b(y.w);
    return r;
}

__global__ __launch_bounds__(64) void stage_kernel(
    const unsigned short* __restrict__ Bsw,
    const unsigned short* __restrict__ sxwb,
    const unsigned short* __restrict__ tywb,
    const float* __restrict__ bvec,
    float* __restrict__ out, int v)
{
    const int lane = threadIdx.x;
    const int cellid = blockIdx.x >> 2;
    const int stripe = blockIdx.x & 3;

    int ilo0 = (v > T-1) ? v-(T-1) : 0, ihi0 = (v < S-1) ? v : S-1;
    int n0 = (v <= S+T-2) ? (ihi0 - ilo0 + 1) : 0;
    if (n0 < 0) n0 = 0;
    int w1 = v - 1;
    int ilo1 = (w1 > T-1) ? w1-(T-1) : 0;

    int d, i, j;
    if (cellid < n0) { d = 0; i = ilo0 + cellid; j = v - i; }
    else             { d = 1; int q = cellid - n0; i = ilo1 + q; j = w1 - i; }

    const int r0   = stripe * 16;
    const int arow = r0 + (lane & 15);
    const int kk0  = (lane >> 4) * 8;
    const int colq = lane & 15;
    const int rowq = r0 + ((lane >> 4) << 2);

#define OUTB(dd,ii,jj,ch) (out + ((((size_t)(dd)*S + (ii))*T + (jj))*2 + (ch)) * (size_t)(B*H))

    if (d == 0) {
        f32x4 acc[16];
#pragma unroll
        for (int t = 0; t < 16; ++t) acc[t] = (f32x4)(0.f);
        if (i > 0) {
            const float* topM = OUTB(0, i-1, j, 0);
            const unsigned short* Bt = Bsw + 0*MSZ;
            for (int kt = 0; kt < 8; ++kt) {
                s16x8 a = make_afrag(topM, arow, kt*32 + kk0);
                const unsigned short* bp = Bt + (kt*H + colq)*32 + kk0;
#pragma unroll
                for (int ct = 0; ct < 16; ++ct)
                    acc[ct] = __builtin_amdgcn_mfma_f32_16x16x32_bf16(a, *(const s16x8*)(bp + ct*512), acc[ct], 0, 0, 0);
            }
        }
        if (j > 0) {
            const float* lftM = OUTB(0, i, j-1, 0);
            const unsigned short* Bl = Bsw + 1*MSZ;
            for (int kt = 0; kt < 8; ++kt) {
                s16x8 a = make_afrag(lftM, arow, kt*32 + kk0);
                const unsigned short* bp = Bl + (kt*H + colq)*32 + kk0;
#pragma unroll
                for (int ct = 0; ct < 16; ++ct)
                    acc[ct] = __builtin_amdgcn_mfma_f32_16x16x32_bf16(a, *(const s16x8*)(bp + ct*512), acc[ct], 0, 0, 0);
            }
        }
        const unsigned short* xwp = sxwb + (size_t)i * B * H;
        const unsigned short* ywp = tywb + (size_t)j * B * H;
        float* ox = OUTB(0, i, j, 0);
        float* oy = OUTB(0, i, j, 1);
#pragma unroll
        for (int ct = 0; ct < 16; ++ct) {
            int col = ct*16 + colq;
            float bc = bvec[col];
#pragma unroll
            for (int q = 0; q < 4; ++q) {
                int row = rowq + q;
                float rec = acc[ct][q] + bc;
                ox[row*H + col] = tanh_fast(b2f(xwp[row*H + col]) + rec);
                oy[row*H + col] = tanh_fast(b2f(ywp[row*H + col]) + rec);
            }
        }
    } else {
        const float* hx0 = OUTB(0, i, j, 0);
        const float* hy0 = OUTB(0, i, j, 1);
        const float* topM = (i > 0) ? OUTB(1, i-1, j, 0) : (const float*)0;
        const float* lftM = (j > 0) ? OUTB(1, i, j-1, 0) : (const float*)0;
        const unsigned short* BU1t = Bsw + 2*MSZ;
        const unsigned short* BU1l = Bsw + 3*MSZ;
        const unsigned short* BW1  = Bsw + 4*MSZ;
        float* ox = OUTB(1, i, j, 0);
        float* oy = OUTB(1, i, j, 1);

        for (int halfc = 0; halfc < 2; ++halfc) {
            f32x4 arr[8], axx[8], ayy[8];
#pragma unroll
            for (int t = 0; t < 8; ++t) { arr[t]=(f32x4)(0.f); axx[t]=(f32x4)(0.f); ayy[t]=(f32x4)(0.f); }
            const int bbase = halfc*4096 + colq*32 + kk0;

            for (int kt = 0; kt < 8; ++kt) {
                const int k0 = kt*32 + kk0;
                const int bofs = kt*H*32 + bbase;
                if (topM) {
                    s16x8 a = make_afrag(topM, arow, k0);
#pragma unroll
                    for (int ct = 0; ct < 8; ++ct)
                        arr[ct] = __builtin_amdgcn_mfma_f32_16x16x32_bf16(a, *(const s16x8*)(BU1t + bofs + ct*512), arr[ct], 0, 0, 0);
                }
                if (lftM) {
                    s16x8 a = make_afrag(lftM, arow, k0);
#pragma unroll
                    for (int ct = 0; ct < 8; ++ct)
                        arr[ct] = __builtin_amdgcn_mfma_f32_16x16x32_bf16(a, *(const s16x8*)(BU1l + bofs + ct*512), arr[ct], 0, 0, 0);
                }
                {
                    s16x8 a = make_afrag(hx0, arow, k0);
#pragma unroll
                    for (int ct = 0; ct < 8; ++ct)
                        axx[ct] = __builtin_amdgcn_mfma_f32_16x16x32_bf16(a, *(const s16x8*)(BW1 + bofs + ct*512), axx[ct], 0, 0, 0);
                }
                {
                    s16x8 a = make_afrag(hy0, arow, k0);
#pragma unroll
                    for (int ct = 0; ct < 8; ++ct)
                        ayy[ct] = __builtin_amdgcn_mfma_f32_16x16x32_bf16(a, *(const s16x8*)(BW1 + bofs + ct*512), ayy[ct], 0, 0, 0);
                }
            }
#pragma unroll
            for (int ct = 0; ct < 8; ++ct) {
                int col = halfc*128 + ct*16 + colq;
                float bc = bvec[H + col];
#pragma unroll
                for (int q = 0; q < 4; ++q) {
                    int row = rowq + q;
                    float rec = arr[ct][q] + bc;
                    ox[row*H + col] = tanh_fast(axx[ct][q] + rec);
                    oy[row*H + col] = tanh_fast(ayy[ct][q] + rec);
                }
            }
        }
    }
#undef OUTB
}

// ============================ host launcher ================================
extern "C" void kernel_launch(void* const* d_in, const int* in_sizes, int n_in,
                              void* d_out, int out_size, void* d_ws, size_t ws_size,
                              hipStream_t stream)
{
    const float* src = (const float*)d_in[0];
    const float* trg = (const float*)d_in[1];
    const float* W   = (const float*)d_in[2];
    const float* U   = (const float*)d_in[3];
    const float* b   = (const float*)d_in[4];
    float* out = (float*)d_out;

    const int nflags = 3 * S * T;
    const size_t need_stage   = (size_t)5*MSZ*2 + (size_t)2*S*B*H*2;
    const size_t need_persist = need_stage + (size_t)nflags*sizeof(int);

    unsigned short* Bsw  = (unsigned short*)d_ws;
    unsigned short* sxwb = Bsw + (size_t)5*MSZ;
    unsigned short* tywb = sxwb + (size_t)S*B*H;
    int* flags = (int*)(tywb + (size_t)S*B*H);

    if (ws_size >= need_persist) {
        prep_kernel<<<(5*MSZ + 255)/256, 256, 0, stream>>>(U, W, Bsw);
        proj0b_kernel<<<2*S*B/ROWSP, 256, 0, stream>>>(src, trg, W, sxwb, tywb);
        zeroflags_kernel<<<(nflags + 255)/256, 256, 0, stream>>>(flags, nflags);
        grid_kernel<<<192, 512, 0, stream>>>(Bsw, sxwb, tywb, b, out, flags);
        return;
    }

    // -------- staged fallback --------
    prep_kernel<<<(5*MSZ + 255)/256, 256, 0, stream>>>(U, W, Bsw);
    proj0b_kernel<<<2*S*B/ROWSP, 256, 0, stream>>>(src, trg, W, sxwb, tywb);
    for (int v = 0; v < S + T; ++v) {
        int ilo0 = (v > T-1) ? v-(T-1) : 0, ihi0 = (v < S-1) ? v : S-1;
        int n0 = (v <= S+T-2) ? (ihi0 - ilo0 + 1) : 0;
        if (n0 < 0) n0 = 0;
        int n1 = 0;
        int w1 = v - 1;
        if (w1 >= 0) {
            int ilo1 = (w1 > T-1) ? w1-(T-1) : 0, ihi1 = (w1 < S-1) ? w1 : S-1;
            n1 = ihi1 - ilo1 + 1;
        }
        stage_kernel<<<4*(n0+n1), 64, 0, stream>>>(Bsw, sxwb, tywb, b, out, v);
    }
}

// Round 13
// 624.153 us; speedup vs baseline: 4.7969x; 1.0275x over previous
//
#include <hip/hip_runtime.h>
#include <math.h>

#define S 32
#define T 32
#define B 64
#define H 256
#define MSZ 65536   // elements per swizzled bf16 matrix [8 kt][256 col][32 kk]
#define ROWSP 16

typedef __attribute__((ext_vector_type(8))) short s16x8;
typedef __attribute__((ext_vector_type(4))) float f32x4;

__device__ inline unsigned short f2b(float f){
    unsigned u = __builtin_bit_cast(unsigned, f);
    u += 0x7fffu + ((u >> 16) & 1u);          // RNE
    return (unsigned short)(u >> 16);
}
__device__ inline float b2f(unsigned short s){
    unsigned u = ((unsigned)s) << 16;
    return __builtin_bit_cast(float, u);
}
__device__ inline float tanh_fast(float x){
    float e = __builtin_amdgcn_exp2f(x * 2.8853900817779268f);
    float r = __builtin_amdgcn_rcpf(e + 1.0f);
    return fmaf(-2.0f, r, 1.0f);
}
__device__ inline void waitflag(int* f, int target){
    while (__hip_atomic_load(f, __ATOMIC_RELAXED, __HIP_MEMORY_SCOPE_AGENT) < target)
        __builtin_amdgcn_s_sleep(2);
    (void)__hip_atomic_load(f, __ATOMIC_ACQUIRE, __HIP_MEMORY_SCOPE_AGENT);
}

// ---------------- prep: swizzle U (both depths, top/left) + W[1] to bf16 ----
// Bsw[m][kt][c][kk] = M_m[kt*32+kk][c];  m: 0=U0t 1=U0l 2=U1t 3=U1l 4=W1
__global__ __launch_bounds__(256) void prep_kernel(
    const float* __restrict__ U, const float* __restrict__ W,
    unsigned short* __restrict__ Bsw)
{
    int t = blockIdx.x * 256 + threadIdx.x;
    if (t >= 5 * MSZ) return;
    int m  = t >> 16;
    int r  = t & 65535;
    int kt = r >> 13;
    int r2 = r & 8191;
    int c  = r2 >> 5;
    int kk = r2 & 31;
    int krow = kt * 32 + kk;
    float v;
    if (m < 4){ int d = m >> 1, ope = m & 1; v = U[((size_t)d*2*H + ope*H + krow)*H + c]; }
    else      { v = W[((size_t)H + krow)*H + c]; }   // W[1]
    Bsw[t] = f2b(v);
}

// ---------------- depth-0 projections (bf16 out): sxw = src@W0, tyw = trg@W0
__global__ __launch_bounds__(256) void proj0b_kernel(
    const float* __restrict__ src, const float* __restrict__ trg,
    const float* __restrict__ W0, unsigned short* __restrict__ sxw,
    unsigned short* __restrict__ tyw)
{
    const int c = threadIdx.x;
    int gr0 = blockIdx.x * ROWSP;
    const float* inp; unsigned short* outp; int r0;
    if (gr0 < S * B) { inp = src; outp = sxw; r0 = gr0; }
    else             { inp = trg; outp = tyw; r0 = gr0 - S * B; }

    float acc[ROWSP];
#pragma unroll
    for (int rr = 0; rr < ROWSP; ++rr) acc[rr] = 0.f;
    for (int k = 0; k < H; ++k) {
        float wv = W0[k * H + c];
#pragma unroll
        for (int rr = 0; rr < ROWSP; ++rr)
            acc[rr] = fmaf(inp[(size_t)(r0 + rr) * H + k], wv, acc[rr]);
    }
#pragma unroll
    for (int rr = 0; rr < ROWSP; ++rr)
        outp[(size_t)(r0 + rr) * H + c] = f2b(acc[rr]);
}

__global__ __launch_bounds__(256) void zeroflags_kernel(int* flags, int n){
    int t = blockIdx.x * 256 + threadIdx.x;
    if (t < n) flags[t] = 0;
}

// ---------------- persistent dataflow grid kernel (R12 + 2-barrier phases) -
// 192 blocks: 0..63 d0 (row=(blk&63)>>1, half=blk&1); 64..127 d1; 128..191
// proj. Each operand phase: poll(1 barrier) -> full 32KB stage -> 1 barrier
// -> 32 MFMAs. LDS: 4 x 16KB slots (left=0,1; top=2,3; proj hx=0,1 hy=2,3).
__global__ __launch_bounds__(512, 2) void grid_kernel(
    const unsigned short* __restrict__ Bsw,
    const unsigned short* __restrict__ sxwb,
    const unsigned short* __restrict__ tywb,
    const float* __restrict__ bvec,
    float* __restrict__ out,
    int* __restrict__ flags)
{
    __shared__ unsigned short Alds[4 * 64 * 128];   // 64 KB
    char* AldsB = (char*)Alds;

    const int blk   = blockIdx.x;
    const int btyp  = blk >> 6;         // 0=d0, 1=d1, 2=proj
    const int i     = (blk & 63) >> 1;
    const int half  = blk & 1;
    const int c0    = half * 128;

    const int tid  = threadIdx.x;
    const int lane = tid & 63;
    const int wv   = tid >> 6;          // wave 0..7, owns 16 cols
    const int colq = lane & 15;
    const int hi   = lane >> 4;
    const int kk0  = hi * 8;
    const int col  = c0 + wv * 16 + colq;
    const int hi16 = hi * 16;
    const int lswz = (colq & 7) << 4;   // A-frag read swizzle (row&7 == colq&7)

    const int row64 = tid >> 3;         // staging row 0..63
    const int k4b   = (tid & 7) * 4;    // staging float4 base within 32
    const int swz   = (row64 & 7) << 4; // staging write swizzle

    int* flag0 = flags;
    int* flag1 = flags + S * T;
    int* flagg = flags + 2 * S * T;

    const size_t CH = (size_t)B * H;
#define OPTR(dd,ii,jj,ch) (out + ((((size_t)(dd)*S + (ii))*T + (jj))*2 + (ch)) * CH)

#define LOADC(LB, SP, KC) do { \
    const float* _p = (SP) + (size_t)row64 * H + (KC)*128 + k4b*4; \
    L[(LB)+0] = *(const float4*)(_p); \
    L[(LB)+1] = *(const float4*)(_p + 4); \
    L[(LB)+2] = *(const float4*)(_p + 8); \
    L[(LB)+3] = *(const float4*)(_p + 12); \
} while(0)

#define WRITEC(SLOT, LB) do { \
    _Pragma("unroll") \
    for (int _l = 0; _l < 4; ++_l) { \
        float4 _v = L[(LB)+_l]; \
        uint2 _u; \
        _u.x = f2b(_v.x) | ((unsigned)f2b(_v.y) << 16); \
        _u.y = f2b(_v.z) | ((unsigned)f2b(_v.w) << 16); \
        *(uint2*)(AldsB + (SLOT)*16384 + row64*256 + (((k4b+_l)*8) ^ swz)) = _u; \
    } \
} while(0)

#define AFRAG(SLOT, RT, KTL) (*(const s16x8*)(AldsB + (SLOT)*16384 + ((RT)*16 + colq)*256 + ((((KTL)*64) + hi16) ^ lswz)))

// one staged operand, 2 barriers: poll -> sync -> full 32KB stage -> sync ->
// 32 MFMAs (kt0..3 from SLOT, kt4..7 from SLOT+1). ACC += A_op x BF.
#define OPPHASE2(SLOT, FP, TGT, SPTR, BF, ACC) do { \
    if (tid == 0) waitflag((FP), (TGT)); \
    __syncthreads(); \
    const float* _sp = (SPTR); \
    LOADC(0, _sp, 0); \
    LOADC(4, _sp, 1); \
    WRITEC(SLOT, 0); \
    WRITEC((SLOT)+1, 4); \
    __syncthreads(); \
    _Pragma("unroll") \
    for (int _kt = 0; _kt < 8; ++_kt) { \
        const int _sl = (SLOT) + (_kt >> 2); \
        _Pragma("unroll") \
        for (int _rt = 0; _rt < 4; ++_rt) \
            ACC[_rt] = __builtin_amdgcn_mfma_f32_16x16x32_bf16(AFRAG(_sl,_rt,_kt & 3), BF[_kt], ACC[_rt], 0, 0, 0); \
    } \
} while(0)

    if (btyp == 0) {
        // ===================== depth-0 =====================
        s16x8 bfT[8], bfL[8];
#pragma unroll
        for (int kt = 0; kt < 8; ++kt) {
            int o = (kt * H + col) * 32 + kk0;
            bfT[kt] = *(const s16x8*)(Bsw + o);
            bfL[kt] = *(const s16x8*)(Bsw + (size_t)MSZ + o);
        }
        // xw is j-invariant: registers once
        unsigned short xwr[16];
        {
            const unsigned short* xwp = sxwb + (size_t)i * B * H;
#pragma unroll
            for (int rt = 0; rt < 4; ++rt)
#pragma unroll
                for (int q = 0; q < 4; ++q)
                    xwr[rt*4+q] = xwp[(size_t)(rt*16 + hi*4 + q) * H + col];
        }

        for (int j = 0; j < T; ++j) {
            // yw: issue loads before any polling
            unsigned short ywr[16];
            {
                const unsigned short* ywp = tywb + (size_t)j * B * H;
#pragma unroll
                for (int rt = 0; rt < 4; ++rt)
#pragma unroll
                    for (int q = 0; q < 4; ++q)
                        ywr[rt*4+q] = ywp[(size_t)(rt*16 + hi*4 + q) * H + col];
            }

            f32x4 acc[4];
#pragma unroll
            for (int rt = 0; rt < 4; ++rt) acc[rt] = (f32x4)(0.f);
            float4 L[8];

            if (j > 0)
                OPPHASE2(0, &flag0[i*T + (j-1)], 2, OPTR(0, i, j-1, 0), bfL, acc);
            if (i > 0)
                OPPHASE2(2, &flag0[(i-1)*T + j], 2, OPTR(0, i-1, j, 0), bfT, acc);

            float* ox = OPTR(0, i, j, 0);
            float* oy = OPTR(0, i, j, 1);
            const float bc = bvec[col];
#pragma unroll
            for (int rt = 0; rt < 4; ++rt)
#pragma unroll
                for (int q = 0; q < 4; ++q) {
                    int idx = rt*4 + q;
                    int row = rt*16 + hi*4 + q;
                    float rec = acc[rt][q] + bc;
                    float hx = tanh_fast(b2f(xwr[idx]) + rec);
                    float hy = tanh_fast(b2f(ywr[idx]) + rec);
                    __hip_atomic_store(&ox[row*H + col], hx, __ATOMIC_RELAXED, __HIP_MEMORY_SCOPE_AGENT);
                    __hip_atomic_store(&oy[row*H + col], hy, __ATOMIC_RELAXED, __HIP_MEMORY_SCOPE_AGENT);
                }

            asm volatile("s_waitcnt vmcnt(0)" ::: "memory");
            __syncthreads();
            if (tid == 0)
                __hip_atomic_fetch_add(&flag0[i*T + j], 1, __ATOMIC_RELEASE, __HIP_MEMORY_SCOPE_AGENT);
        }
    } else if (btyp == 1) {
        // ===================== depth-1 =====================
        s16x8 bfT[8], bfL[8];
#pragma unroll
        for (int kt = 0; kt < 8; ++kt) {
            int o = (kt * H + col) * 32 + kk0;
            bfT[kt] = *(const s16x8*)(Bsw + (size_t)2*MSZ + o);
            bfL[kt] = *(const s16x8*)(Bsw + (size_t)3*MSZ + o);
        }

        for (int j = 0; j < T; ++j) {
            // poll gg (stale: proj shadows d0, which runs ahead of us), then
            // issue px/py register loads early — latency hides under phases
            if (tid == 0) waitflag(&flagg[i*T + j], 2);
            __syncthreads();
            float pxr[16], pyr[16];
            {
                const float* p0s = OPTR(1, i, j, 0);
                const float* p1s = OPTR(1, i, j, 1);
#pragma unroll
                for (int rt = 0; rt < 4; ++rt)
#pragma unroll
                    for (int q = 0; q < 4; ++q) {
                        int idx = rt*4 + q;
                        int row = rt*16 + hi*4 + q;
                        pxr[idx] = p0s[row*H + col];
                        pyr[idx] = p1s[row*H + col];
                    }
            }

            f32x4 ar[4];
#pragma unroll
            for (int rt = 0; rt < 4; ++rt) ar[rt] = (f32x4)(0.f);
            float4 L[8];

            if (j > 0)
                OPPHASE2(0, &flag1[i*T + (j-1)], 2, OPTR(1, i, j-1, 0), bfL, ar);
            if (i > 0)
                OPPHASE2(2, &flag1[(i-1)*T + j], 2, OPTR(1, i-1, j, 0), bfT, ar);

            // epilogue: hx1 (consumed) -> drain -> publish; hy1 (dead) after
            float recs[16];
            float* ox = OPTR(1, i, j, 0);
            const float bc = bvec[H + col];
#pragma unroll
            for (int rt = 0; rt < 4; ++rt)
#pragma unroll
                for (int q = 0; q < 4; ++q) {
                    int idx = rt*4 + q;
                    int row = rt*16 + hi*4 + q;
                    float rec = ar[rt][q] + bc;
                    recs[idx] = rec;
                    float hx = tanh_fast(pxr[idx] + rec);
                    __hip_atomic_store(&ox[row*H + col], hx, __ATOMIC_RELAXED, __HIP_MEMORY_SCOPE_AGENT);
                }
            asm volatile("s_waitcnt vmcnt(0)" ::: "memory");
            __syncthreads();
            if (tid == 0)
                __hip_atomic_fetch_add(&flag1[i*T + j], 1, __ATOMIC_RELEASE, __HIP_MEMORY_SCOPE_AGENT);

            float* oy = OPTR(1, i, j, 1);
#pragma unroll
            for (int rt = 0; rt < 4; ++rt)
#pragma unroll
                for (int q = 0; q < 4; ++q) {
                    int idx = rt*4 + q;
                    int row = rt*16 + hi*4 + q;
                    float hy = tanh_fast(pyr[idx] + recs[idx]);
                    __hip_atomic_store(&oy[row*H + col], hy, __ATOMIC_RELAXED, __HIP_MEMORY_SCOPE_AGENT);
                }
        }
    } else {
        // ===================== projection (no self-chain) =====================
        s16x8 bfW[8];
#pragma unroll
        for (int kt = 0; kt < 8; ++kt)
            bfW[kt] = *(const s16x8*)(Bsw + (size_t)4*MSZ + (kt * H + col) * 32 + kk0);

        for (int j = 0; j < T; ++j) {
            if (tid == 0) waitflag(&flag0[i*T + j], 2);
            __syncthreads();

            f32x4 px[4], py[4];
#pragma unroll
            for (int rt = 0; rt < 4; ++rt) { px[rt] = (f32x4)(0.f); py[rt] = (f32x4)(0.f); }
            float4 L[16];

            const float* sHx0 = OPTR(0, i, j, 0);
            const float* sHy0 = OPTR(0, i, j, 1);
            LOADC(0,  sHx0, 0);
            LOADC(4,  sHx0, 1);
            LOADC(8,  sHy0, 0);
            LOADC(12, sHy0, 1);
            WRITEC(0, 0); WRITEC(1, 4); WRITEC(2, 8); WRITEC(3, 12);
            __syncthreads();
#pragma unroll
            for (int kt = 0; kt < 8; ++kt) {
                const int slx = (kt >> 2);
                const int sly = 2 + (kt >> 2);
#pragma unroll
                for (int rt = 0; rt < 4; ++rt) {
                    px[rt] = __builtin_amdgcn_mfma_f32_16x16x32_bf16(AFRAG(slx,rt,kt & 3), bfW[kt], px[rt], 0, 0, 0);
                    py[rt] = __builtin_amdgcn_mfma_f32_16x16x32_bf16(AFRAG(sly,rt,kt & 3), bfW[kt], py[rt], 0, 0, 0);
                }
            }

            float* p0 = OPTR(1, i, j, 0);
            float* p1 = OPTR(1, i, j, 1);
#pragma unroll
            for (int rt = 0; rt < 4; ++rt)
#pragma unroll
                for (int q = 0; q < 4; ++q) {
                    int row = rt*16 + hi*4 + q;
                    __hip_atomic_store(&p0[row*H + col], px[rt][q], __ATOMIC_RELAXED, __HIP_MEMORY_SCOPE_AGENT);
                    __hip_atomic_store(&p1[row*H + col], py[rt][q], __ATOMIC_RELAXED, __HIP_MEMORY_SCOPE_AGENT);
                }
            asm volatile("s_waitcnt vmcnt(0)" ::: "memory");
            __syncthreads();
            if (tid == 0)
                __hip_atomic_fetch_add(&flagg[i*T + j], 1, __ATOMIC_RELEASE, __HIP_MEMORY_SCOPE_AGENT);
        }
    }
#undef OPTR
#undef LOADC
#undef WRITEC
#undef AFRAG
#undef OPPHASE2
}

// =================== staged fallback (round-2 structure) ===================
__device__ inline s16x8 make_afrag(const float* __restrict__ M, int arow, int k0){
    const float* p = M + arow * H + k0;
    float4 x = *(const float4*)(p);
    float4 y = *(const float4*)(p + 4);
    s16x8 r;
    r[0]=(short)f2b(x.x); r[1]=(short)f2b(x.y); r[2]=(short)f2b(x.z); r[3]=(short)f2b(x.w);
    r[4]=(short)f2b(y.x); r[5]=(short)f2b(y.y); r[6]=(short)f2b(y.z); r[7]=(short)f2b(y.w);
    return r;
}

__global__ __launch_bounds__(64) void stage_kernel(
    const unsigned short* __restrict__ Bsw,
    const unsigned short* __restrict__ sxwb,
    const unsigned short* __restrict__ tywb,
    const float* __restrict__ bvec,
    float* __restrict__ out, int v)
{
    const int lane = threadIdx.x;
    const int cellid = blockIdx.x >> 2;
    const int stripe = blockIdx.x & 3;

    int ilo0 = (v > T-1) ? v-(T-1) : 0, ihi0 = (v < S-1) ? v : S-1;
    int n0 = (v <= S+T-2) ? (ihi0 - ilo0 + 1) : 0;
    if (n0 < 0) n0 = 0;
    int w1 = v - 1;
    int ilo1 = (w1 > T-1) ? w1-(T-1) : 0;

    int d, i, j;
    if (cellid < n0) { d = 0; i = ilo0 + cellid; j = v - i; }
    else             { d = 1; int q = cellid - n0; i = ilo1 + q; j = w1 - i; }

    const int r0   = stripe * 16;
    const int arow = r0 + (lane & 15);
    const int kk0  = (lane >> 4) * 8;
    const int colq = lane & 15;
    const int rowq = r0 + ((lane >> 4) << 2);

#define OUTB(dd,ii,jj,ch) (out + ((((size_t)(dd)*S + (ii))*T + (jj))*2 + (ch)) * (size_t)(B*H))

    if (d == 0) {
        f32x4 acc[16];
#pragma unroll
        for (int t = 0; t < 16; ++t) acc[t] = (f32x4)(0.f);
        if (i > 0) {
            const float* topM = OUTB(0, i-1, j, 0);
            const unsigned short* Bt = Bsw + 0*MSZ;
            for (int kt = 0; kt < 8; ++kt) {
                s16x8 a = make_afrag(topM, arow, kt*32 + kk0);
                const unsigned short* bp = Bt + (kt*H + colq)*32 + kk0;
#pragma unroll
                for (int ct = 0; ct < 16; ++ct)
                    acc[ct] = __builtin_amdgcn_mfma_f32_16x16x32_bf16(a, *(const s16x8*)(bp + ct*512), acc[ct], 0, 0, 0);
            }
        }
        if (j > 0) {
            const float* lftM = OUTB(0, i, j-1, 0);
            const unsigned short* Bl = Bsw + 1*MSZ;
            for (int kt = 0; kt < 8; ++kt) {
                s16x8 a = make_afrag(lftM, arow, kt*32 + kk0);
                const unsigned short* bp = Bl + (kt*H + colq)*32 + kk0;
#pragma unroll
                for (int ct = 0; ct < 16; ++ct)
                    acc[ct] = __builtin_amdgcn_mfma_f32_16x16x32_bf16(a, *(const s16x8*)(bp + ct*512), acc[ct], 0, 0, 0);
            }
        }
        const unsigned short* xwp = sxwb + (size_t)i * B * H;
        const unsigned short* ywp = tywb + (size_t)j * B * H;
        float* ox = OUTB(0, i, j, 0);
        float* oy = OUTB(0, i, j, 1);
#pragma unroll
        for (int ct = 0; ct < 16; ++ct) {
            int col = ct*16 + colq;
            float bc = bvec[col];
#pragma unroll
            for (int q = 0; q < 4; ++q) {
                int row = rowq + q;
                float rec = acc[ct][q] + bc;
                ox[row*H + col] = tanh_fast(b2f(xwp[row*H + col]) + rec);
                oy[row*H + col] = tanh_fast(b2f(ywp[row*H + col]) + rec);
            }
        }
    } else {
        const float* hx0 = OUTB(0, i, j, 0);
        const float* hy0 = OUTB(0, i, j, 1);
        const float* topM = (i > 0) ? OUTB(1, i-1, j, 0) : (const float*)0;
        const float* lftM = (j > 0) ? OUTB(1, i, j-1, 0) : (const float*)0;
        const unsigned short* BU1t = Bsw + 2*MSZ;
        const unsigned short* BU1l = Bsw + 3*MSZ;
        const unsigned short* BW1  = Bsw + 4*MSZ;
        float* ox = OUTB(1, i, j, 0);
        float* oy = OUTB(1, i, j, 1);

        for (int halfc = 0; halfc < 2; ++halfc) {
            f32x4 arr[8], axx[8], ayy[8];
#pragma unroll
            for (int t = 0; t < 8; ++t) { arr[t]=(f32x4)(0.f); axx[t]=(f32x4)(0.f); ayy[t]=(f32x4)(0.f); }
            const int bbase = halfc*4096 + colq*32 + kk0;

            for (int kt = 0; kt < 8; ++kt) {
                const int k0 = kt*32 + kk0;
                const int bofs = kt*H*32 + bbase;
                if (topM) {
                    s16x8 a = make_afrag(topM, arow, k0);
#pragma unroll
                    for (int ct = 0; ct < 8; ++ct)
                        arr[ct] = __builtin_amdgcn_mfma_f32_16x16x32_bf16(a, *(const s16x8*)(BU1t + bofs + ct*512), arr[ct], 0, 0, 0);
                }
                if (lftM) {
                    s16x8 a = make_afrag(lftM, arow, k0);
#pragma unroll
                    for (int ct = 0; ct < 8; ++ct)
                        arr[ct] = __builtin_amdgcn_mfma_f32_16x16x32_bf16(a, *(const s16x8*)(BU1l + bofs + ct*512), arr[ct], 0, 0, 0);
                }
                {
                    s16x8 a = make_afrag(hx0, arow, k0);
#pragma unroll
                    for (int ct = 0; ct < 8; ++ct)
                        axx[ct] = __builtin_amdgcn_mfma_f32_16x16x32_bf16(a, *(const s16x8*)(BW1 + bofs + ct*512), axx[ct], 0, 0, 0);
                }
                {
                    s16x8 a = make_afrag(hy0, arow, k0);
#pragma unroll
                    for (int ct = 0; ct < 8; ++ct)
                        ayy[ct] = __builtin_amdgcn_mfma_f32_16x16x32_bf16(a, *(const s16x8*)(BW1 + bofs + ct*512), ayy[ct], 0, 0, 0);
                }
            }
#pragma unroll
            for (int ct = 0; ct < 8; ++ct) {
                int col = halfc*128 + ct*16 + colq;
                float bc = bvec[H + col];
#pragma unroll
                for (int q = 0; q < 4; ++q) {
                    int row = rowq + q;
                    float rec = arr[ct][q] + bc;
                    ox[row*H + col] = tanh_fast(axx[ct][q] + rec);
                    oy[row*H + col] = tanh_fast(ayy[ct][q] + rec);
                }
            }
        }
    }
#undef OUTB
}

// ============================ host launcher ================================
extern "C" void kernel_launch(void* const* d_in, const int* in_sizes, int n_in,
                              void* d_out, int out_size, void* d_ws, size_t ws_size,
                              hipStream_t stream)
{
    const float* src = (const float*)d_in[0];
    const float* trg = (const float*)d_in[1];
    const float* W   = (const float*)d_in[2];
    const float* U   = (const float*)d_in[3];
    const float* b   = (const float*)d_in[4];
    float* out = (float*)d_out;

    const int nflags = 3 * S * T;
    const size_t need_stage   = (size_t)5*MSZ*2 + (size_t)2*S*B*H*2;
    const size_t need_persist = need_stage + (size_t)nflags*sizeof(int);

    unsigned short* Bsw  = (unsigned short*)d_ws;
    unsigned short* sxwb = Bsw + (size_t)5*MSZ;
    unsigned short* tywb = sxwb + (size_t)S*B*H;
    int* flags = (int*)(tywb + (size_t)S*B*H);

    if (ws_size >= need_persist) {
        prep_kernel<<<(5*MSZ + 255)/256, 256, 0, stream>>>(U, W, Bsw);
        proj0b_kernel<<<2*S*B/ROWSP, 256, 0, stream>>>(src, trg, W, sxwb, tywb);
        zeroflags_kernel<<<(nflags + 255)/256, 256, 0, stream>>>(flags, nflags);
        grid_kernel<<<192, 512, 0, stream>>>(Bsw, sxwb, tywb, b, out, flags);
        return;
    }

    // -------- staged fallback --------
    prep_kernel<<<(5*MSZ + 255)/256, 256, 0, stream>>>(U, W, Bsw);
    proj0b_kernel<<<2*S*B/ROWSP, 256, 0, stream>>>(src, trg, W, sxwb, tywb);
    for (int v = 0; v < S + T; ++v) {
        int ilo0 = (v > T-1) ? v-(T-1) : 0, ihi0 = (v < S-1) ? v : S-1;
        int n0 = (v <= S+T-2) ? (ihi0 - ilo0 + 1) : 0;
        if (n0 < 0) n0 = 0;
        int n1 = 0;
        int w1 = v - 1;
        if (w1 >= 0) {
            int ilo1 = (w1 > T-1) ? w1-(T-1) : 0, ihi1 = (w1 < S-1) ? w1 : S-1;
            n1 = ihi1 - ilo1 + 1;
        }
        stage_kernel<<<4*(n0+n1), 64, 0, stream>>>(Bsw, sxwb, tywb, b, out, v);
    }
}